// Round 19
// baseline (158.039 us; speedup 1.0000x reference)
//
#include <hip/hip_runtime.h>
#include <hip/hip_bf16.h>
#include <math.h>

#define B_ 2
#define S_ 2048
#define D_ 1024
#define H_ 4
#define DK_ 256
#define NJ 24
#define NG 96
#define KTA 128
#define NT2 (S_ / KTA)
#define NTL (NT2 / 2)

typedef _Float16 f16;
typedef _Float16 f16x2 __attribute__((ext_vector_type(2)));
typedef _Float16 f16x4 __attribute__((ext_vector_type(4)));
typedef _Float16 f16x8 __attribute__((ext_vector_type(8)));
typedef float f32x16 __attribute__((ext_vector_type(16)));
typedef float v2f __attribute__((ext_vector_type(2)));

// ---------------- fused prep: fuse | fuse_bias | expand | wcvt | vt ----------------
__global__ __launch_bounds__(256) void k_prep(
    const float* __restrict__ Wq_w, const float* __restrict__ proj_w,
    const float* __restrict__ Wq_b, const float* __restrict__ proj_b,
    const float* __restrict__ Wo_w, const float* __restrict__ V,
    f16* __restrict__ Mf, f16* __restrict__ Mkf,
    float* __restrict__ cbias, float* __restrict__ pbias,
    f16* __restrict__ Wf, f16* __restrict__ Vt2) {
  __shared__ f16 tile[64][72];
  const int bid = blockIdx.x;
  const int t = threadIdx.x;
  if (bid < 384) {
    int tid = bid * 256 + t;
    int hj = tid >> 10, d = tid & 1023;
    int h = hj / NJ, j = hj - h * NJ;
    const float* wq = Wq_w + (size_t)(h * DK_) * D_ + d;
    const float* pw = proj_w + j * DK_;
    float acc = 0.f;
#pragma unroll 8
    for (int k = 0; k < DK_; ++k) acc += wq[(size_t)k * D_] * pw[k];
    Mf[(size_t)hj * D_ + d] = (f16)acc;
  } else if (bid == 384) {
    if (t < NG) {
      int h = t / NJ, j = t - h * NJ;
      float acc = proj_b[j];
      for (int k = 0; k < DK_; ++k) acc += Wq_b[h * DK_ + k] * proj_w[j * DK_ + k];
      cbias[t] = acc;
      pbias[t] = proj_b[j];
    }
  } else if (bid < 769) {
    int tid = (bid - 385) * 256 + t;
    int hj = tid >> 10, d = tid & 1023;
    int h = hj / NJ, j = hj - h * NJ;
    float v = ((d >> 8) == h) ? proj_w[j * DK_ + (d & 255)] : 0.f;
    Mkf[tid] = (f16)v;
  } else if (bid < 1281) {
    int i = ((bid - 769) * 256 + t) * 8;
    float4 a = *(const float4*)(Wo_w + i);
    float4 b = *(const float4*)(Wo_w + i + 4);
    f16x8 o = {(f16)a.x, (f16)a.y, (f16)a.z, (f16)a.w,
               (f16)b.x, (f16)b.y, (f16)b.z, (f16)b.w};
    *(f16x8*)(Wf + i) = o;
  } else {
    int vbid = bid - 1281;
    int s0 = (vbid & 31) * 64, c0 = ((vbid >> 5) & 3) * 64;
    int bh = vbid >> 7;
    int b = bh >> 2, h = bh & 3;
    const float* src = V + (size_t)b * S_ * D_ + h * DK_ + c0;
#pragma unroll
    for (int u = 0; u < 4; ++u) {
      int row = (t >> 4) + 16 * u;
      int c4 = (t & 15) * 4;
      float4 v = *(const float4*)(src + (size_t)(s0 + row) * D_ + c4);
      tile[c4 + 0][row] = (f16)v.x;
      tile[c4 + 1][row] = (f16)v.y;
      tile[c4 + 2][row] = (f16)v.z;
      tile[c4 + 3][row] = (f16)v.w;
    }
    __syncthreads();
#pragma unroll
    for (int u = 0; u < 2; ++u) {
      int sid = t + 256 * u;
      int sgroup = sid & 7, dkl = sid >> 3;
      int dk = c0 + dkl, s = s0 + sgroup * 8;
      int wv = dk >> 5, qq = dk & 31;
      int kt = s >> 7, ks = (s >> 4) & 7, lhh = (s >> 3) & 1;
      size_t idx = ((((size_t)(bh * 8 + wv) * 16 + kt) * 8 + ks) * 2 + lhh) * 256 + qq * 8;
      *(f16x8*)(Vt2 + idx) = *(const f16x8*)&tile[dkl][sgroup * 8];
    }
  }
}

// ---------------- unified gen via f16 MFMA + psi ----------------
__global__ __launch_bounds__(256, 1) void k_gen(
    const float* __restrict__ Q, const float* __restrict__ Kin,
    const f16* __restrict__ Mf, const f16* __restrict__ Mkf,
    const float* __restrict__ cbias, const float* __restrict__ pbias,
    f16* __restrict__ pqF, float* __restrict__ qn2,
    f16* __restrict__ pkF, float* __restrict__ kn2) {
  __shared__ __align__(16) f16 Xs[8192];
  __shared__ __align__(16) f16 Bs[24576];
  __shared__ __align__(16) float redP[4][32][96];
  __shared__ float genL[32][100];

  const int t = threadIdx.x;
  const int w = t >> 6, lane = t & 63;
  const int l31 = lane & 31, lh = lane >> 5;
  const bool isQ = blockIdx.x < 128;
  const int r0 = (isQ ? blockIdx.x : blockIdx.x - 128) * 32;
  const float* X = isQ ? Q : Kin;
  const f16* Bf = isQ ? Mf : Mkf;
  const float* bias = isQ ? cbias : pbias;

  int xrow[8], xk4[8];
#pragma unroll
  for (int u = 0; u < 8; ++u) {
    int idx = t + 256 * u;
    xrow[u] = idx >> 6;
    xk4[u] = idx & 63;
  }
  int bcol[12], bkg[12];
#pragma unroll
  for (int u = 0; u < 12; ++u) {
    int idx = t + 256 * u;
    bcol[u] = idx >> 5;
    bkg[u] = idx & 31;
  }

  float4 xr[8];
  f16x8 br[12];
#define XLOAD(K0)                                                              \
  {                                                                            \
    _Pragma("unroll") for (int u = 0; u < 8; ++u) xr[u] =                      \
        *(const float4*)(X + (size_t)(r0 + xrow[u]) * D_ + (K0) + xk4[u] * 4); \
  }
#define BLOAD(K0)                                                            \
  {                                                                          \
    _Pragma("unroll") for (int u = 0; u < 12; ++u) br[u] =                   \
        *(const f16x8*)(Bf + (size_t)bcol[u] * D_ + (K0) + bkg[u] * 8);      \
  }
#define XWRITE()                                                            \
  {                                                                         \
    _Pragma("unroll") for (int u = 0; u < 8; ++u) {                         \
      f16x4 v = {(f16)xr[u].x, (f16)xr[u].y, (f16)xr[u].z, (f16)xr[u].w};   \
      *(f16x4*)&Xs[((xk4[u] >> 1) * 32 + xrow[u]) * 8 + (xk4[u] & 1) * 4] = v; \
    }                                                                       \
  }
#define BWRITE()                                                            \
  {                                                                         \
    _Pragma("unroll") for (int u = 0; u < 12; ++u)                          \
        *(f16x8*)&Bs[(bcol[u] >> 5) * 8192 + bkg[u] * 256 +                 \
                     (bcol[u] & 31) * 8] = br[u];                           \
  }

  XLOAD(0);
  BLOAD(0);
  XWRITE();
  BWRITE();
  __syncthreads();

  f32x16 acc0{}, acc1{}, acc2{};
  for (int ch = 0; ch < 4; ++ch) {
    if (ch < 3) {
      XLOAD((ch + 1) * 256);
      BLOAD((ch + 1) * 256);
    }
#pragma unroll
    for (int i = 0; i < 4; ++i) {
      const int kk = w * 4 + i;
      const int off = (kk * 2 + lh) * 256 + l31 * 8;
      f16x8 af = *(const f16x8*)&Xs[off];
      f16x8 b0 = *(const f16x8*)&Bs[off];
      f16x8 b1 = *(const f16x8*)&Bs[8192 + off];
      f16x8 b2 = *(const f16x8*)&Bs[16384 + off];
      acc0 = __builtin_amdgcn_mfma_f32_32x32x16_f16(af, b0, acc0, 0, 0, 0);
      acc1 = __builtin_amdgcn_mfma_f32_32x32x16_f16(af, b1, acc1, 0, 0, 0);
      acc2 = __builtin_amdgcn_mfma_f32_32x32x16_f16(af, b2, acc2, 0, 0, 0);
    }
    __syncthreads();
    if (ch < 3) {
      XWRITE();
      BWRITE();
      __syncthreads();
    }
  }
#undef XLOAD
#undef BLOAD
#undef XWRITE
#undef BWRITE

#pragma unroll
  for (int r = 0; r < 16; ++r) {
    const int row = (r & 3) + 8 * (r >> 2) + 4 * lh;
    redP[w][row][l31] = acc0[r];
    redP[w][row][32 + l31] = acc1[r];
    redP[w][row][64 + l31] = acc2[r];
  }
  __syncthreads();

  {
    const int row = t >> 3, cg = t & 7;
#pragma unroll
    for (int c = 0; c < 12; ++c) {
      int col = cg * 12 + c;
      genL[row][col] = redP[0][row][col] + redP[1][row][col] +
                       redP[2][row][col] + redP[3][row][col] + bias[col];
    }
  }
  __syncthreads();

  {
    const int rg = t >> 6;
    const int hh = (t & 63) >> 4;
    const int ii = t & 15;
    const int j = ii & 7;
    f16* po = isQ ? pqF : pkF;
    float* n2o = isQ ? qn2 : kn2;
#pragma unroll 2
    for (int r = 0; r < 8; ++r) {
      int row = rg * 8 + r;
      int g = r0 + row;
      int b = g >> 11, s = g & (S_ - 1);
      const float* gl = &genL[row][hh * NJ];
      float A = gl[j], Bg = gl[8 + j];
      float Th = fminf(fmaxf(gl[16 + j], -8.f), 8.f);
      float val = (ii < 8) ? (A * expf(Th) + Bg * cosf(Th)) : (Bg * sinf(Th));
      size_t base = (size_t)(b * H_ + hh) * S_ + s;
      po[base * 16 + ii] = (f16)val;
      float sq = val * val;
#pragma unroll
      for (int off = 1; off < 16; off <<= 1) sq += __shfl_xor(sq, off);
      if (ii == 0) n2o[base] = sq;
    }
  }
}

// ---------------- per-bh khmax ----------------
__global__ __launch_bounds__(256) void k_kmax(const float* __restrict__ kn2,
                                              float* __restrict__ khm) {
  __shared__ float red[4];
  const int bh = blockIdx.x, t = threadIdx.x;
  float m = 0.f;
#pragma unroll
  for (int u = 0; u < 8; ++u) m = fmaxf(m, kn2[(size_t)bh * S_ + t + 256 * u]);
#pragma unroll
  for (int off = 1; off < 64; off <<= 1) m = fmaxf(m, __shfl_xor(m, off));
  if ((t & 63) == 0) red[t >> 6] = m;
  __syncthreads();
  if (t == 0) {
    float mm = fmaxf(fmaxf(red[0], red[1]), fmaxf(red[2], red[3]));
    khm[bh] = sqrtf(mm + 1e-6f);
  }
}

// ---------------- MFMA flash geometric attention, static-max softmax (exp2) ----------------
__global__ __launch_bounds__(512, 4) void k_attn(
    const f16* __restrict__ pqF, const float* __restrict__ qn2,
    const f16* __restrict__ pkF, const float* __restrict__ kn2,
    const f16* __restrict__ Vt2, const float* __restrict__ geo_w,
    const float* __restrict__ temp, const float* __restrict__ khm,
    float* __restrict__ pacc, float* __restrict__ pml) {
  __shared__ __align__(16) float kn2s[2][KTA];
  __shared__ __align__(16) float khs[2][KTA];
  __shared__ float sPart[8][32];
  __shared__ __align__(16) f16 Plds[2][16][32][8];

  const int t = threadIdx.x;
  const int w = t >> 6;
  const int lane = t & 63;
  const int q_ = lane & 31;
  const int lh = lane >> 5;

  const int bid = blockIdx.x;
  const int half = bid >> 9;
  const int inner = bid & 511;
  const int bh = inner & 7, qt = inner >> 3;
  const int q0 = qt * 32;
  const int kofs = half * (S_ / 2);

  const size_t bhS = (size_t)bh * S_;
  const f16* pkb = pkF + bhS * 16;
  const float* kn2b = kn2 + bhS + kofs;

  // exp2 domain: all coefficients pre-scaled by log2(e)
  const float scale = 0.25f / temp[0] * 1.4426950408889634f;
  const float g0s = geo_w[0] * scale, g1s = geo_w[1] * scale, g2s = geo_w[2] * scale;
  const float g3s = geo_w[3] * scale;

  const f16x8 bq = *(const f16x8*)(pqF + (bhS + q0 + q_) * 16 + lh * 8);
  const float qn2q = qn2[bhS + q0 + q_];
  const float qh = sqrtf(qn2q + 1e-6f);
  const float qh3 = qh * g3s;
  const float sumg = fabsf(g0s) + fabsf(g1s) + fabsf(g2s) + fabsf(g3s);
  const float Mhat = sumg * qh * khm[bh] - 4.328085123f;  // 3*log2(e)

  const v2f qn2v = {qn2q, qn2q};
  const v2f g0v = {g0s, g0s}, g1v = {g1s, g1s}, g2v = {g2s, g2s};
  const v2f zero2 = {0.f, 0.f}, eps2 = {1e-6f, 1e-6f};
  const v2f mhv = {Mhat, Mhat};

  const f16* ap_base = pkb + (size_t)(kofs + w * 16 + (q_ & 15)) * 16 +
                       ((q_ < 16) ? lh * 8 : (1 - lh) * 8);
  const f16* vb_lane = Vt2 + ((size_t)(bh * 8 + w) * 16 + half * NTL) * 4096 +
                       lh * 256 + q_ * 8;

  if (t < KTA) { float kv = kn2b[t]; kn2s[0][t] = kv; khs[0][t] = sqrtf(kv + 1e-6f); }
  float lreg = 0.f;
  f32x16 acc{};
  const f32x16 zacc{};

  f16x8 af = *(const f16x8*)ap_base;
  f16x8 bv[8];
#pragma unroll
  for (int ks = 0; ks < 8; ++ks) bv[ks] = *(const f16x8*)(vb_lane + ks * 512);
  __syncthreads();

  for (int ktl = 0; ktl < NTL; ++ktl) {
    const int k0l = ktl * KTA;
    const int cb = ktl & 1, nb = cb ^ 1;

    float knv = 0.f;
    if (t < KTA && ktl + 1 < NTL) knv = kn2b[k0l + KTA + t];

    f16x8 afx = af;
    if (q_ >= 16 && lh == 1) afx = -afx;
    __builtin_amdgcn_s_setprio(1);
    f32x16 sc = __builtin_amdgcn_mfma_f32_32x32x16_f16(afx, bq, zacc, 0, 0, 0);
    __builtin_amdgcn_s_setprio(0);
    if (ktl + 1 < NTL) af = *(const f16x8*)(ap_base + (size_t)(k0l + KTA) * 16);

    float pv[8];
    v2f psv = {0.f, 0.f};
#pragma unroll
    for (int rp = 0; rp < 4; ++rp) {
      const int r = 2 * rp;
      const int kb2 = w * 16 + 4 * lh + (rp & 1) * 2 + (rp >> 1) * 8;
      v2f tn = {sc[r], sc[r + 1]};
      v2f sp = {sc[r + 8], sc[r + 9]};
      v2f kn2p = *(const v2f*)&kn2s[cb][kb2];
      v2f khp = *(const v2f*)&khs[cb][kb2];
      v2f wr = qn2v * kn2p - tn * tn - sp * sp;
      wr = __builtin_elementwise_max(wr, zero2) + eps2;
      v2f wg = {sqrtf(wr.x), sqrtf(wr.y)};
      v2f sv2 = g0v * wg + g1v * tn + g2v * sp + qh3 * khp - mhv;
      v2f p2 = {exp2f(sv2.x), exp2f(sv2.y)};
      pv[r] = p2.x;
      pv[r + 1] = p2.y;
      psv += p2;
    }
    lreg += psv.x + psv.y;

    if (t < KTA && ktl + 1 < NTL) {
      kn2s[nb][t] = knv;
      khs[nb][t] = sqrtf(knv + 1e-6f);
    }
    {
      f16x2 p01 = {(f16)pv[0], (f16)pv[1]};
      f16x2 p23 = {(f16)pv[2], (f16)pv[3]};
      f16x2 p45 = {(f16)pv[4], (f16)pv[5]};
      f16x2 p67 = {(f16)pv[6], (f16)pv[7]};
      *(f16x2*)&Plds[cb][2 * w + 0][q_][4 * lh + 0] = p01;
      *(f16x2*)&Plds[cb][2 * w + 0][q_][4 * lh + 2] = p23;
      *(f16x2*)&Plds[cb][2 * w + 1][q_][4 * lh + 0] = p45;
      *(f16x2*)&Plds[cb][2 * w + 1][q_][4 * lh + 2] = p67;
    }
    __syncthreads();  // single barrier per tile

    __builtin_amdgcn_s_setprio(1);
#pragma unroll
    for (int ks = 0; ks < 8; ++ks) {
      f16x8 pa = *(const f16x8*)&Plds[cb][2 * ks + lh][q_][0];
      acc = __builtin_amdgcn_mfma_f32_32x32x16_f16(pa, bv[ks], acc, 0, 0, 0);
    }
    __builtin_amdgcn_s_setprio(0);
    if (ktl + 1 < NTL) {
      const f16* vbn = vb_lane + (size_t)(ktl + 1) * 4096;
#pragma unroll
      for (int ks = 0; ks < 8; ++ks) bv[ks] = *(const f16x8*)(vbn + ks * 512);
    }
  }

  lreg += __shfl_xor(lreg, 32);
  if (lh == 0) sPart[w][q_] = lreg;
  __syncthreads();
  if (t < 32) {
    float s8 = 0.f;
#pragma unroll
    for (int i = 0; i < 8; ++i) s8 += sPart[i][t];
    pml[(size_t)bid * 64 + t] = s8;
  }
#pragma unroll
  for (int r = 0; r < 16; ++r) {
    const int row = (r & 3) + 8 * (r >> 2) + 4 * lh;
    pacc[((size_t)bid * 32 + row) * 256 + w * 32 + q_] = acc[r];
  }
}

// ---------------- output projection fused with split-K merge ----------------
__global__ __launch_bounds__(256, 1) void k_wo(const float* __restrict__ pacc,
                                               const float* __restrict__ pml,
                                               const f16* __restrict__ Wt,
                                               const float* __restrict__ bias,
                                               float* __restrict__ C) {
  __shared__ __align__(16) f16 Abuf[2][128 * 64];
  __shared__ __align__(16) f16 Bbuf[2][128 * 64];
  __shared__ float linvL[128][4];
  const int t = threadIdx.x;
  const int w = t >> 6, lane = t & 63;
  const int wr = w >> 1, wc = w & 1;
  const int brow = blockIdx.y * 128, bcol = blockIdx.x * 128;

  int srow[4], skof[4], ibase[4], qrow[4];
#pragma unroll
  for (int u = 0; u < 4; ++u) {
    int c = t + 256 * u;
    int sub = c >> 6, l6 = c & 63;
    srow[u] = (sub >> 2) * 32 + (l6 & 31);
    skof[u] = (sub & 3) * 16 + (l6 >> 5) * 8;
    int grow = brow + srow[u];
    int b = grow >> 11, s = grow & 2047;
    ibase[u] = (s >> 5) * 8 + b * 4;
    qrow[u] = s & 31;
  }
#pragma unroll
  for (int it = 0; it < 2; ++it) {
    int idx = t + 256 * it;
    int row = idx >> 2, h = idx & 3;
    int grow = brow + row;
    int b = grow >> 11, s = grow & 2047;
    int inner = (s >> 5) * 8 + b * 4 + h;
    int q = s & 31;
    float l = pml[(size_t)inner * 64 + q] + pml[(size_t)(inner + 512) * 64 + q];
    linvL[row][h] = 1.f / l;
  }

  float4 ra[4][4];
  uint4 rb[4];
#define LOAD_TILE(K0)                                                         \
  {                                                                           \
    _Pragma("unroll") for (int u = 0; u < 4; ++u) {                           \
      int k0u = (K0) + skof[u];                                               \
      int h = k0u >> 8, dk = k0u & 255;                                       \
      size_t i0 = ((size_t)((ibase[u] + h) * 32 + qrow[u])) * 256 + dk;       \
      size_t i1 = i0 + (size_t)512 * 32 * 256;                                \
      ra[u][0] = *(const float4*)(pacc + i0);                                 \
      ra[u][1] = *(const float4*)(pacc + i0 + 4);                             \
      ra[u][2] = *(const float4*)(pacc + i1);                                 \
      ra[u][3] = *(const float4*)(pacc + i1 + 4);                             \
      rb[u] = *(const uint4*)(Wt + (size_t)(bcol + srow[u]) * D_ + k0u);      \
    }                                                                         \
  }
#define WRITE_TILE(BUF, K0)                                                   \
  {                                                                           \
    _Pragma("unroll") for (int u = 0; u < 4; ++u) {                           \
      int h = ((K0) + skof[u]) >> 8;                                          \
      float lv = linvL[srow[u]][h];                                           \
      float4 s0 = ra[u][0], s1 = ra[u][1], s2 = ra[u][2], s3 = ra[u][3];      \
      f16x8 o = {(f16)((s0.x + s2.x) * lv), (f16)((s0.y + s2.y) * lv),        \
                 (f16)((s0.z + s2.z) * lv), (f16)((s0.w + s2.w) * lv),        \
                 (f16)((s1.x + s3.x) * lv), (f16)((s1.y + s3.y) * lv),        \
                 (f16)((s1.z + s3.z) * lv), (f16)((s1.w + s3.w) * lv)};       \
      *(f16x8*)&Abuf[BUF][(t + 256 * u) * 8] = o;                             \
      *(uint4*)&Bbuf[BUF][(t + 256 * u) * 8] = rb[u];                         \
    }                                                                         \
  }

  f32x16 acc00{}, acc01{}, acc10{}, acc11{};

  LOAD_TILE(0);
  __syncthreads();  // linvL ready
  WRITE_TILE(0, 0);
  LOAD_TILE(64);
  __syncthreads();

  int cur = 0;
  for (int kt = 0; kt < 16; ++kt) {
    const int am0 = (wr * 2 + 0) * 4, am1 = (wr * 2 + 1) * 4;
    const int bn0 = (wc * 2 + 0) * 4, bn1 = (wc * 2 + 1) * 4;
#pragma unroll
    for (int kk = 0; kk < 4; ++kk) {
      f16x8 a0 = *(const f16x8*)&Abuf[cur][(am0 + kk) * 512 + lane * 8];
      f16x8 a1 = *(const f16x8*)&Abuf[cur][(am1 + kk) * 512 + lane * 8];
      f16x8 b0 = *(const f16x8*)&Bbuf[cur][(bn0 + kk) * 512 + lane * 8];
      f16x8 b1 = *(const f16x8*)&Bbuf[cur][(bn1 + kk) * 512 + lane * 8];
      acc00 = __builtin_amdgcn_mfma_f32_32x32x16_f16(a0, b0, acc00, 0, 0, 0);
      acc01 = __builtin_amdgcn_mfma_f32_32x32x16_f16(a0, b1, acc01, 0, 0, 0);
      acc10 = __builtin_amdgcn_mfma_f32_32x32x16_f16(a1, b0, acc10, 0, 0, 0);
      acc11 = __builtin_amdgcn_mfma_f32_32x32x16_f16(a1, b1, acc11, 0, 0, 0);
    }
    if (kt + 1 < 16) {
      WRITE_TILE(cur ^ 1, (kt + 1) * 64);
      if (kt + 2 < 16) LOAD_TILE((kt + 2) * 64);
    }
    __syncthreads();
    cur ^= 1;
  }

  const int l31 = lane & 31, lh = lane >> 5;
  const float bv0 = bias[bcol + (wc * 2 + 0) * 32 + l31];
  const float bv1 = bias[bcol + (wc * 2 + 1) * 32 + l31];
#pragma unroll
  for (int r = 0; r < 16; ++r) {
    const int row = (r & 3) + 8 * (r >> 2) + 4 * lh;
    const size_t m0r = (size_t)(brow + (wr * 2 + 0) * 32 + row) * D_;
    const size_t m1r = (size_t)(brow + (wr * 2 + 1) * 32 + row) * D_;
    C[m0r + bcol + (wc * 2 + 0) * 32 + l31] = acc00[r] + bv0;
    C[m0r + bcol + (wc * 2 + 1) * 32 + l31] = acc01[r] + bv1;
    C[m1r + bcol + (wc * 2 + 0) * 32 + l31] = acc10[r] + bv0;
    C[m1r + bcol + (wc * 2 + 1) * 32 + l31] = acc11[r] + bv1;
  }
#undef LOAD_TILE
#undef WRITE_TILE
}

extern "C" void kernel_launch(void* const* d_in, const int* in_sizes, int n_in,
                              void* d_out, int out_size, void* d_ws, size_t ws_size,
                              hipStream_t stream) {
  const float* Q_input = (const float*)d_in[0];
  const float* K = (const float*)d_in[1];
  const float* V = (const float*)d_in[2];
  const float* Wq_w = (const float*)d_in[4];
  const float* Wq_b = (const float*)d_in[5];
  const float* Wo_w = (const float*)d_in[6];
  const float* Wo_b = (const float*)d_in[7];
  const float* proj_w = (const float*)d_in[8];
  const float* proj_b = (const float*)d_in[9];
  const float* geo_w = (const float*)d_in[10];
  const float* temp = (const float*)d_in[11];

  float* ws = (float*)d_ws;
  float* cbias = ws;                       // 128 f32
  float* pbias = cbias + 128;              // 128
  float* khm = pbias + 128;                // 128 (8 used)
  f16* Mf = (f16*)(khm + 128);             // 98304 f16
  f16* Mkf = Mf + 98304;                   // 98304 f16
  float* qn2 = (float*)(Mkf + 98304);      // 16384 f32
  float* kn2 = qn2 + 16384;                // 16384 f32
  f16* pqF = (f16*)(kn2 + 16384);          // 262144 f16
  f16* pkF = pqF + 262144;                 // 262144 f16
  f16* Vt2 = pkF + 262144;                 // 4194304 f16 (B*S*D — FULL size, R17 bug)
  f16* Wf = Vt2 + 4194304;                 // 1048576 f16
  float* pacc = (float*)(Wf + 1048576);    // 8388608 f32
  float* pml = pacc + 8388608;             // 65536 f32
  float* out = (float*)d_out;

  k_prep<<<dim3(2305), dim3(256), 0, stream>>>(Wq_w, proj_w, Wq_b, proj_b, Wo_w,
                                               V, Mf, Mkf, cbias, pbias, Wf, Vt2);
  k_gen<<<dim3(256), dim3(256), 0, stream>>>(Q_input, K, Mf, Mkf, cbias, pbias,
                                             pqF, qn2, pkF, kn2);
  k_kmax<<<dim3(8), dim3(256), 0, stream>>>(kn2, khm);
  k_attn<<<dim3(1024), dim3(512), 0, stream>>>(pqF, qn2, pkF, kn2, Vt2, geo_w,
                                               temp, khm, pacc, pml);
  k_wo<<<dim3(8, 32), dim3(256), 0, stream>>>(pacc, pml, Wf, Wo_b, out);
}

// Round 20
// 128.164 us; speedup vs baseline: 1.2331x; 1.2331x over previous
//
#include <hip/hip_runtime.h>
#include <hip/hip_bf16.h>
#include <math.h>

#define B_ 2
#define S_ 2048
#define D_ 1024
#define H_ 4
#define DK_ 256
#define NJ 24
#define NG 96
#define KTA 128
#define NT2 (S_ / KTA)
#define NTL (NT2 / 2)

typedef _Float16 f16;
typedef _Float16 f16x2 __attribute__((ext_vector_type(2)));
typedef _Float16 f16x4 __attribute__((ext_vector_type(4)));
typedef _Float16 f16x8 __attribute__((ext_vector_type(8)));
typedef float f32x16 __attribute__((ext_vector_type(16)));
typedef float v2f __attribute__((ext_vector_type(2)));

// ---------------- fused prep: fuse | fuse_bias | expand | wcvt | vt ----------------
__global__ __launch_bounds__(256) void k_prep(
    const float* __restrict__ Wq_w, const float* __restrict__ proj_w,
    const float* __restrict__ Wq_b, const float* __restrict__ proj_b,
    const float* __restrict__ Wo_w, const float* __restrict__ V,
    f16* __restrict__ Mf, f16* __restrict__ Mkf,
    float* __restrict__ cbias, float* __restrict__ pbias,
    f16* __restrict__ Wf, f16* __restrict__ Vt2) {
  __shared__ f16 tile[64][72];
  const int bid = blockIdx.x;
  const int t = threadIdx.x;
  if (bid < 384) {
    int tid = bid * 256 + t;
    int hj = tid >> 10, d = tid & 1023;
    int h = hj / NJ, j = hj - h * NJ;
    const float* wq = Wq_w + (size_t)(h * DK_) * D_ + d;
    const float* pw = proj_w + j * DK_;
    float acc = 0.f;
#pragma unroll 8
    for (int k = 0; k < DK_; ++k) acc += wq[(size_t)k * D_] * pw[k];
    Mf[(size_t)hj * D_ + d] = (f16)acc;
  } else if (bid == 384) {
    if (t < NG) {
      int h = t / NJ, j = t - h * NJ;
      float acc = proj_b[j];
      for (int k = 0; k < DK_; ++k) acc += Wq_b[h * DK_ + k] * proj_w[j * DK_ + k];
      cbias[t] = acc;
      pbias[t] = proj_b[j];
    }
  } else if (bid < 769) {
    int tid = (bid - 385) * 256 + t;
    int hj = tid >> 10, d = tid & 1023;
    int h = hj / NJ, j = hj - h * NJ;
    float v = ((d >> 8) == h) ? proj_w[j * DK_ + (d & 255)] : 0.f;
    Mkf[tid] = (f16)v;
  } else if (bid < 1281) {
    int i = ((bid - 769) * 256 + t) * 8;
    float4 a = *(const float4*)(Wo_w + i);
    float4 b = *(const float4*)(Wo_w + i + 4);
    f16x8 o = {(f16)a.x, (f16)a.y, (f16)a.z, (f16)a.w,
               (f16)b.x, (f16)b.y, (f16)b.z, (f16)b.w};
    *(f16x8*)(Wf + i) = o;
  } else {
    int vbid = bid - 1281;
    int s0 = (vbid & 31) * 64, c0 = ((vbid >> 5) & 3) * 64;
    int bh = vbid >> 7;
    int b = bh >> 2, h = bh & 3;
    const float* src = V + (size_t)b * S_ * D_ + h * DK_ + c0;
#pragma unroll
    for (int u = 0; u < 4; ++u) {
      int row = (t >> 4) + 16 * u;
      int c4 = (t & 15) * 4;
      float4 v = *(const float4*)(src + (size_t)(s0 + row) * D_ + c4);
      tile[c4 + 0][row] = (f16)v.x;
      tile[c4 + 1][row] = (f16)v.y;
      tile[c4 + 2][row] = (f16)v.z;
      tile[c4 + 3][row] = (f16)v.w;
    }
    __syncthreads();
#pragma unroll
    for (int u = 0; u < 2; ++u) {
      int sid = t + 256 * u;
      int sgroup = sid & 7, dkl = sid >> 3;
      int dk = c0 + dkl, s = s0 + sgroup * 8;
      int wv = dk >> 5, qq = dk & 31;
      int kt = s >> 7, ks = (s >> 4) & 7, lhh = (s >> 3) & 1;
      size_t idx = ((((size_t)(bh * 8 + wv) * 16 + kt) * 8 + ks) * 2 + lhh) * 256 + qq * 8;
      *(f16x8*)(Vt2 + idx) = *(const f16x8*)&tile[dkl][sgroup * 8];
    }
  }
}

// ---------------- unified gen via f16 MFMA + psi ----------------
__global__ __launch_bounds__(256, 1) void k_gen(
    const float* __restrict__ Q, const float* __restrict__ Kin,
    const f16* __restrict__ Mf, const f16* __restrict__ Mkf,
    const float* __restrict__ cbias, const float* __restrict__ pbias,
    f16* __restrict__ pqF, float* __restrict__ qn2,
    f16* __restrict__ pkF, float* __restrict__ kn2) {
  __shared__ __align__(16) f16 Xs[8192];
  __shared__ __align__(16) f16 Bs[24576];
  __shared__ __align__(16) float redP[4][32][96];
  __shared__ float genL[32][100];

  const int t = threadIdx.x;
  const int w = t >> 6, lane = t & 63;
  const int l31 = lane & 31, lh = lane >> 5;
  const bool isQ = blockIdx.x < 128;
  const int r0 = (isQ ? blockIdx.x : blockIdx.x - 128) * 32;
  const float* X = isQ ? Q : Kin;
  const f16* Bf = isQ ? Mf : Mkf;
  const float* bias = isQ ? cbias : pbias;

  int xrow[8], xk4[8];
#pragma unroll
  for (int u = 0; u < 8; ++u) {
    int idx = t + 256 * u;
    xrow[u] = idx >> 6;
    xk4[u] = idx & 63;
  }
  int bcol[12], bkg[12];
#pragma unroll
  for (int u = 0; u < 12; ++u) {
    int idx = t + 256 * u;
    bcol[u] = idx >> 5;
    bkg[u] = idx & 31;
  }

  float4 xr[8];
  f16x8 br[12];
#define XLOAD(K0)                                                              \
  {                                                                            \
    _Pragma("unroll") for (int u = 0; u < 8; ++u) xr[u] =                      \
        *(const float4*)(X + (size_t)(r0 + xrow[u]) * D_ + (K0) + xk4[u] * 4); \
  }
#define BLOAD(K0)                                                            \
  {                                                                          \
    _Pragma("unroll") for (int u = 0; u < 12; ++u) br[u] =                   \
        *(const f16x8*)(Bf + (size_t)bcol[u] * D_ + (K0) + bkg[u] * 8);      \
  }
#define XWRITE()                                                            \
  {                                                                         \
    _Pragma("unroll") for (int u = 0; u < 8; ++u) {                         \
      f16x4 v = {(f16)xr[u].x, (f16)xr[u].y, (f16)xr[u].z, (f16)xr[u].w};   \
      *(f16x4*)&Xs[((xk4[u] >> 1) * 32 + xrow[u]) * 8 + (xk4[u] & 1) * 4] = v; \
    }                                                                       \
  }
#define BWRITE()                                                            \
  {                                                                         \
    _Pragma("unroll") for (int u = 0; u < 12; ++u)                          \
        *(f16x8*)&Bs[(bcol[u] >> 5) * 8192 + bkg[u] * 256 +                 \
                     (bcol[u] & 31) * 8] = br[u];                           \
  }

  XLOAD(0);
  BLOAD(0);
  XWRITE();
  BWRITE();
  __syncthreads();

  f32x16 acc0{}, acc1{}, acc2{};
  for (int ch = 0; ch < 4; ++ch) {
    if (ch < 3) {
      XLOAD((ch + 1) * 256);
      BLOAD((ch + 1) * 256);
    }
#pragma unroll
    for (int i = 0; i < 4; ++i) {
      const int kk = w * 4 + i;
      const int off = (kk * 2 + lh) * 256 + l31 * 8;
      f16x8 af = *(const f16x8*)&Xs[off];
      f16x8 b0 = *(const f16x8*)&Bs[off];
      f16x8 b1 = *(const f16x8*)&Bs[8192 + off];
      f16x8 b2 = *(const f16x8*)&Bs[16384 + off];
      acc0 = __builtin_amdgcn_mfma_f32_32x32x16_f16(af, b0, acc0, 0, 0, 0);
      acc1 = __builtin_amdgcn_mfma_f32_32x32x16_f16(af, b1, acc1, 0, 0, 0);
      acc2 = __builtin_amdgcn_mfma_f32_32x32x16_f16(af, b2, acc2, 0, 0, 0);
    }
    __syncthreads();
    if (ch < 3) {
      XWRITE();
      BWRITE();
      __syncthreads();
    }
  }
#undef XLOAD
#undef BLOAD
#undef XWRITE
#undef BWRITE

#pragma unroll
  for (int r = 0; r < 16; ++r) {
    const int row = (r & 3) + 8 * (r >> 2) + 4 * lh;
    redP[w][row][l31] = acc0[r];
    redP[w][row][32 + l31] = acc1[r];
    redP[w][row][64 + l31] = acc2[r];
  }
  __syncthreads();

  {
    const int row = t >> 3, cg = t & 7;
#pragma unroll
    for (int c = 0; c < 12; ++c) {
      int col = cg * 12 + c;
      genL[row][col] = redP[0][row][col] + redP[1][row][col] +
                       redP[2][row][col] + redP[3][row][col] + bias[col];
    }
  }
  __syncthreads();

  {
    const int rg = t >> 6;
    const int hh = (t & 63) >> 4;
    const int ii = t & 15;
    const int j = ii & 7;
    f16* po = isQ ? pqF : pkF;
    float* n2o = isQ ? qn2 : kn2;
#pragma unroll 2
    for (int r = 0; r < 8; ++r) {
      int row = rg * 8 + r;
      int g = r0 + row;
      int b = g >> 11, s = g & (S_ - 1);
      const float* gl = &genL[row][hh * NJ];
      float A = gl[j], Bg = gl[8 + j];
      float Th = fminf(fmaxf(gl[16 + j], -8.f), 8.f);
      float val = (ii < 8) ? (A * expf(Th) + Bg * cosf(Th)) : (Bg * sinf(Th));
      size_t base = (size_t)(b * H_ + hh) * S_ + s;
      po[base * 16 + ii] = (f16)val;
      float sq = val * val;
#pragma unroll
      for (int off = 1; off < 16; off <<= 1) sq += __shfl_xor(sq, off);
      if (ii == 0) n2o[base] = sq;
    }
  }
}

// ---------------- per-bh khmax ----------------
__global__ __launch_bounds__(256) void k_kmax(const float* __restrict__ kn2,
                                              float* __restrict__ khm) {
  __shared__ float red[4];
  const int bh = blockIdx.x, t = threadIdx.x;
  float m = 0.f;
#pragma unroll
  for (int u = 0; u < 8; ++u) m = fmaxf(m, kn2[(size_t)bh * S_ + t + 256 * u]);
#pragma unroll
  for (int off = 1; off < 64; off <<= 1) m = fmaxf(m, __shfl_xor(m, off));
  if ((t & 63) == 0) red[t >> 6] = m;
  __syncthreads();
  if (t == 0) {
    float mm = fmaxf(fmaxf(red[0], red[1]), fmaxf(red[2], red[3]));
    khm[bh] = sqrtf(mm + 1e-6f);
  }
}

// ---------------- MFMA flash geometric attention, static-max softmax (exp2) ----------------
__global__ __launch_bounds__(512, 4) void k_attn(
    const f16* __restrict__ pqF, const float* __restrict__ qn2,
    const f16* __restrict__ pkF, const float* __restrict__ kn2,
    const f16* __restrict__ Vt2, const float* __restrict__ geo_w,
    const float* __restrict__ temp, const float* __restrict__ khm,
    float* __restrict__ pacc, float* __restrict__ pml) {
  __shared__ __align__(16) float kn2s[2][KTA];
  __shared__ __align__(16) float khs[2][KTA];
  __shared__ float sPart[8][32];
  __shared__ __align__(16) f16 Plds[2][16][32][8];

  const int t = threadIdx.x;
  const int w = t >> 6;
  const int lane = t & 63;
  const int q_ = lane & 31;
  const int lh = lane >> 5;

  const int bid = blockIdx.x;
  const int half = bid >> 9;
  const int inner = bid & 511;
  const int bh = inner & 7, qt = inner >> 3;
  const int q0 = qt * 32;
  const int kofs = half * (S_ / 2);

  const size_t bhS = (size_t)bh * S_;
  const f16* pkb = pkF + bhS * 16;
  const float* kn2b = kn2 + bhS + kofs;

  const float scale = 0.25f / temp[0] * 1.4426950408889634f;
  const float g0s = geo_w[0] * scale, g1s = geo_w[1] * scale, g2s = geo_w[2] * scale;
  const float g3s = geo_w[3] * scale;

  const f16x8 bq = *(const f16x8*)(pqF + (bhS + q0 + q_) * 16 + lh * 8);
  const float qn2q = qn2[bhS + q0 + q_];
  const float qh = sqrtf(qn2q + 1e-6f);
  const float qh3 = qh * g3s;
  const float sumg = fabsf(g0s) + fabsf(g1s) + fabsf(g2s) + fabsf(g3s);
  const float Mhat = sumg * qh * khm[bh] - 4.328085123f;

  const v2f qn2v = {qn2q, qn2q};
  const v2f g0v = {g0s, g0s}, g1v = {g1s, g1s}, g2v = {g2s, g2s};
  const v2f zero2 = {0.f, 0.f}, eps2 = {1e-6f, 1e-6f};
  const v2f mhv = {Mhat, Mhat};

  const f16* ap_base = pkb + (size_t)(kofs + w * 16 + (q_ & 15)) * 16 +
                       ((q_ < 16) ? lh * 8 : (1 - lh) * 8);
  const f16* vb_lane = Vt2 + ((size_t)(bh * 8 + w) * 16 + half * NTL) * 4096 +
                       lh * 256 + q_ * 8;

  if (t < KTA) { float kv = kn2b[t]; kn2s[0][t] = kv; khs[0][t] = sqrtf(kv + 1e-6f); }
  float lreg = 0.f;
  f32x16 acc{};
  const f32x16 zacc{};

  f16x8 af = *(const f16x8*)ap_base;
  f16x8 bv[8];
#pragma unroll
  for (int ks = 0; ks < 8; ++ks) bv[ks] = *(const f16x8*)(vb_lane + ks * 512);
  __syncthreads();

  for (int ktl = 0; ktl < NTL; ++ktl) {
    const int k0l = ktl * KTA;
    const int cb = ktl & 1, nb = cb ^ 1;

    float knv = 0.f;
    if (t < KTA && ktl + 1 < NTL) knv = kn2b[k0l + KTA + t];

    f16x8 afx = af;
    if (q_ >= 16 && lh == 1) afx = -afx;
    __builtin_amdgcn_s_setprio(1);
    f32x16 sc = __builtin_amdgcn_mfma_f32_32x32x16_f16(afx, bq, zacc, 0, 0, 0);
    __builtin_amdgcn_s_setprio(0);
    if (ktl + 1 < NTL) af = *(const f16x8*)(ap_base + (size_t)(k0l + KTA) * 16);

    float pv[8];
    v2f psv = {0.f, 0.f};
#pragma unroll
    for (int rp = 0; rp < 4; ++rp) {
      const int r = 2 * rp;
      const int kb2 = w * 16 + 4 * lh + (rp & 1) * 2 + (rp >> 1) * 8;
      v2f tn = {sc[r], sc[r + 1]};
      v2f sp = {sc[r + 8], sc[r + 9]};
      v2f kn2p = *(const v2f*)&kn2s[cb][kb2];
      v2f khp = *(const v2f*)&khs[cb][kb2];
      v2f wr = qn2v * kn2p - tn * tn - sp * sp;
      wr = __builtin_elementwise_max(wr, zero2) + eps2;
      v2f wg = {sqrtf(wr.x), sqrtf(wr.y)};
      v2f sv2 = g0v * wg + g1v * tn + g2v * sp + qh3 * khp - mhv;
      v2f p2 = {exp2f(sv2.x), exp2f(sv2.y)};
      pv[r] = p2.x;
      pv[r + 1] = p2.y;
      psv += p2;
    }
    lreg += psv.x + psv.y;

    if (t < KTA && ktl + 1 < NTL) {
      kn2s[nb][t] = knv;
      khs[nb][t] = sqrtf(knv + 1e-6f);
    }
    {
      f16x2 p01 = {(f16)pv[0], (f16)pv[1]};
      f16x2 p23 = {(f16)pv[2], (f16)pv[3]};
      f16x2 p45 = {(f16)pv[4], (f16)pv[5]};
      f16x2 p67 = {(f16)pv[6], (f16)pv[7]};
      *(f16x2*)&Plds[cb][2 * w + 0][q_][4 * lh + 0] = p01;
      *(f16x2*)&Plds[cb][2 * w + 0][q_][4 * lh + 2] = p23;
      *(f16x2*)&Plds[cb][2 * w + 1][q_][4 * lh + 0] = p45;
      *(f16x2*)&Plds[cb][2 * w + 1][q_][4 * lh + 2] = p67;
    }
    __syncthreads();  // single barrier per tile

    __builtin_amdgcn_s_setprio(1);
#pragma unroll
    for (int ks = 0; ks < 8; ++ks) {
      f16x8 pa = *(const f16x8*)&Plds[cb][2 * ks + lh][q_][0];
      acc = __builtin_amdgcn_mfma_f32_32x32x16_f16(pa, bv[ks], acc, 0, 0, 0);
    }
    __builtin_amdgcn_s_setprio(0);
    if (ktl + 1 < NTL) {
      const f16* vbn = vb_lane + (size_t)(ktl + 1) * 4096;
#pragma unroll
      for (int ks = 0; ks < 8; ++ks) bv[ks] = *(const f16x8*)(vbn + ks * 512);
    }
  }

  lreg += __shfl_xor(lreg, 32);
  if (lh == 0) sPart[w][q_] = lreg;
  __syncthreads();
  if (t < 32) {
    float s8 = 0.f;
#pragma unroll
    for (int i = 0; i < 8; ++i) s8 += sPart[i][t];
    pml[(size_t)bid * 64 + t] = s8;
  }
#pragma unroll
  for (int r = 0; r < 16; ++r) {
    const int row = (r & 3) + 8 * (r >> 2) + 4 * lh;
    pacc[((size_t)bid * 32 + row) * 256 + w * 32 + q_] = acc[r];
  }
}

// ---------------- split-K merge: (a0+a1)/(l0+l1) -> f16 attn ----------------
__global__ __launch_bounds__(256) void k_merge(const float* __restrict__ pacc,
                                               const float* __restrict__ pml,
                                               f16* __restrict__ attnF) {
  const int inner = blockIdx.x;
  const int bh = inner & 7, qt = inner >> 3;
  const int b = bh >> 2, h = bh & 3;
  const int t = threadIdx.x;
  const int q = t >> 3, dgrp = t & 7;
  const float* a0 = pacc + ((size_t)inner * 32 + q) * 256 + dgrp * 32;
  const float* a1 = pacc + ((size_t)(inner + 512) * 32 + q) * 256 + dgrp * 32;
  const float l0 = pml[(size_t)inner * 64 + q];
  const float l1 = pml[(size_t)(inner + 512) * 64 + q];
  const float linv = 1.f / (l0 + l1);
  f16* dst = attnF + ((size_t)b * S_ + qt * 32 + q) * D_ + h * DK_ + dgrp * 32;
#pragma unroll
  for (int i = 0; i < 4; ++i) {
    float4 x0 = ((const float4*)a0)[2 * i];
    float4 y0 = ((const float4*)a0)[2 * i + 1];
    float4 x1 = ((const float4*)a1)[2 * i];
    float4 y1 = ((const float4*)a1)[2 * i + 1];
    f16x8 o = {(f16)((x0.x + x1.x) * linv), (f16)((x0.y + x1.y) * linv),
               (f16)((x0.z + x1.z) * linv), (f16)((x0.w + x1.w) * linv),
               (f16)((y0.x + y1.x) * linv), (f16)((y0.y + y1.y) * linv),
               (f16)((y0.z + y1.z) * linv), (f16)((y0.w + y1.w) * linv)};
    *(f16x8*)(dst + 8 * i) = o;
  }
}

// ---------------- output projection: LDS-staged f16 MFMA GEMM ----------------
__global__ __launch_bounds__(256, 1) void k_wo(const f16* __restrict__ A,
                                               const f16* __restrict__ Wt,
                                               const float* __restrict__ bias,
                                               float* __restrict__ C) {
  __shared__ __align__(16) f16 Abuf[2][128 * 64];
  __shared__ __align__(16) f16 Bbuf[2][128 * 64];
  const int t = threadIdx.x;
  const int w = t >> 6, lane = t & 63;
  const int wr = w >> 1, wc = w & 1;
  const int brow = blockIdx.y * 128, bcol = blockIdx.x * 128;

  int srow[4], skof[4];
#pragma unroll
  for (int u = 0; u < 4; ++u) {
    int c = t + 256 * u;
    int sub = c >> 6, l6 = c & 63;
    srow[u] = (sub >> 2) * 32 + (l6 & 31);
    skof[u] = (sub & 3) * 16 + (l6 >> 5) * 8;
  }

  uint4 ra0, ra1, ra2, ra3, rb0, rb1, rb2, rb3;
#define LOAD_TILE(K0)                                                        \
  {                                                                          \
    ra0 = *(const uint4*)(A + (size_t)(brow + srow[0]) * D_ + (K0) + skof[0]); \
    ra1 = *(const uint4*)(A + (size_t)(brow + srow[1]) * D_ + (K0) + skof[1]); \
    ra2 = *(const uint4*)(A + (size_t)(brow + srow[2]) * D_ + (K0) + skof[2]); \
    ra3 = *(const uint4*)(A + (size_t)(brow + srow[3]) * D_ + (K0) + skof[3]); \
    rb0 = *(const uint4*)(Wt + (size_t)(bcol + srow[0]) * D_ + (K0) + skof[0]); \
    rb1 = *(const uint4*)(Wt + (size_t)(bcol + srow[1]) * D_ + (K0) + skof[1]); \
    rb2 = *(const uint4*)(Wt + (size_t)(bcol + srow[2]) * D_ + (K0) + skof[2]); \
    rb3 = *(const uint4*)(Wt + (size_t)(bcol + srow[3]) * D_ + (K0) + skof[3]); \
  }
#define WRITE_TILE(BUF)                                       \
  {                                                           \
    *(uint4*)&Abuf[BUF][(t + 0) * 8] = ra0;                   \
    *(uint4*)&Abuf[BUF][(t + 256) * 8] = ra1;                 \
    *(uint4*)&Abuf[BUF][(t + 512) * 8] = ra2;                 \
    *(uint4*)&Abuf[BUF][(t + 768) * 8] = ra3;                 \
    *(uint4*)&Bbuf[BUF][(t + 0) * 8] = rb0;                   \
    *(uint4*)&Bbuf[BUF][(t + 256) * 8] = rb1;                 \
    *(uint4*)&Bbuf[BUF][(t + 512) * 8] = rb2;                 \
    *(uint4*)&Bbuf[BUF][(t + 768) * 8] = rb3;                 \
  }

  f32x16 acc00{}, acc01{}, acc10{}, acc11{};

  LOAD_TILE(0);
  WRITE_TILE(0);
  LOAD_TILE(64);
  __syncthreads();

  int cur = 0;
  for (int kt = 0; kt < 16; ++kt) {
    const int am0 = (wr * 2 + 0) * 4, am1 = (wr * 2 + 1) * 4;
    const int bn0 = (wc * 2 + 0) * 4, bn1 = (wc * 2 + 1) * 4;
#pragma unroll
    for (int kk = 0; kk < 4; ++kk) {
      f16x8 a0 = *(const f16x8*)&Abuf[cur][(am0 + kk) * 512 + lane * 8];
      f16x8 a1 = *(const f16x8*)&Abuf[cur][(am1 + kk) * 512 + lane * 8];
      f16x8 b0 = *(const f16x8*)&Bbuf[cur][(bn0 + kk) * 512 + lane * 8];
      f16x8 b1 = *(const f16x8*)&Bbuf[cur][(bn1 + kk) * 512 + lane * 8];
      acc00 = __builtin_amdgcn_mfma_f32_32x32x16_f16(a0, b0, acc00, 0, 0, 0);
      acc01 = __builtin_amdgcn_mfma_f32_32x32x16_f16(a0, b1, acc01, 0, 0, 0);
      acc10 = __builtin_amdgcn_mfma_f32_32x32x16_f16(a1, b0, acc10, 0, 0, 0);
      acc11 = __builtin_amdgcn_mfma_f32_32x32x16_f16(a1, b1, acc11, 0, 0, 0);
    }
    if (kt + 1 < 16) {
      WRITE_TILE(cur ^ 1);
      if (kt + 2 < 16) LOAD_TILE((kt + 2) * 64);
    }
    __syncthreads();
    cur ^= 1;
  }

  const int l31 = lane & 31, lh = lane >> 5;
  const float bv0 = bias[bcol + (wc * 2 + 0) * 32 + l31];
  const float bv1 = bias[bcol + (wc * 2 + 1) * 32 + l31];
#pragma unroll
  for (int r = 0; r < 16; ++r) {
    const int row = (r & 3) + 8 * (r >> 2) + 4 * lh;
    const size_t m0r = (size_t)(brow + (wr * 2 + 0) * 32 + row) * D_;
    const size_t m1r = (size_t)(brow + (wr * 2 + 1) * 32 + row) * D_;
    C[m0r + bcol + (wc * 2 + 0) * 32 + l31] = acc00[r] + bv0;
    C[m0r + bcol + (wc * 2 + 1) * 32 + l31] = acc01[r] + bv1;
    C[m1r + bcol + (wc * 2 + 0) * 32 + l31] = acc10[r] + bv0;
    C[m1r + bcol + (wc * 2 + 1) * 32 + l31] = acc11[r] + bv1;
  }
#undef LOAD_TILE
#undef WRITE_TILE
}

extern "C" void kernel_launch(void* const* d_in, const int* in_sizes, int n_in,
                              void* d_out, int out_size, void* d_ws, size_t ws_size,
                              hipStream_t stream) {
  const float* Q_input = (const float*)d_in[0];
  const float* K = (const float*)d_in[1];
  const float* V = (const float*)d_in[2];
  const float* Wq_w = (const float*)d_in[4];
  const float* Wq_b = (const float*)d_in[5];
  const float* Wo_w = (const float*)d_in[6];
  const float* Wo_b = (const float*)d_in[7];
  const float* proj_w = (const float*)d_in[8];
  const float* proj_b = (const float*)d_in[9];
  const float* geo_w = (const float*)d_in[10];
  const float* temp = (const float*)d_in[11];

  float* ws = (float*)d_ws;
  float* cbias = ws;                       // 128 f32
  float* pbias = cbias + 128;              // 128
  float* khm = pbias + 128;                // 128 (8 used)
  f16* Mf = (f16*)(khm + 128);             // 98304 f16
  f16* Mkf = Mf + 98304;                   // 98304 f16
  float* qn2 = (float*)(Mkf + 98304);      // 16384 f32
  float* kn2 = qn2 + 16384;                // 16384 f32
  f16* pqF = (f16*)(kn2 + 16384);          // 262144 f16
  f16* pkF = pqF + 262144;                 // 262144 f16
  f16* Vt2 = pkF + 262144;                 // 4194304 f16 (full B*S*D)
  f16* attnF = Vt2 + 4194304;              // 4194304 f16
  f16* Wf = attnF + 4194304;               // 1048576 f16
  float* pacc = (float*)(Wf + 1048576);    // 8388608 f32
  float* pml = pacc + 8388608;             // 65536 f32
  float* out = (float*)d_out;

  k_prep<<<dim3(2305), dim3(256), 0, stream>>>(Wq_w, proj_w, Wq_b, proj_b, Wo_w,
                                               V, Mf, Mkf, cbias, pbias, Wf, Vt2);
  k_gen<<<dim3(256), dim3(256), 0, stream>>>(Q_input, K, Mf, Mkf, cbias, pbias,
                                             pqF, qn2, pkF, kn2);
  k_kmax<<<dim3(8), dim3(256), 0, stream>>>(kn2, khm);
  k_attn<<<dim3(1024), dim3(512), 0, stream>>>(pqF, qn2, pkF, kn2, Vt2, geo_w,
                                               temp, khm, pacc, pml);
  k_merge<<<dim3(512), dim3(256), 0, stream>>>(pacc, pml, attnF);
  k_wo<<<dim3(8, 32), dim3(256), 0, stream>>>(attnF, Wf, Wo_b, out);
}

// Round 21
// 115.898 us; speedup vs baseline: 1.3636x; 1.1058x over previous
//
#include <hip/hip_runtime.h>
#include <hip/hip_bf16.h>
#include <math.h>

#define B_ 2
#define S_ 2048
#define D_ 1024
#define H_ 4
#define DK_ 256
#define NJ 24
#define NG 96
#define KTA 128
#define NT2 (S_ / KTA)

typedef _Float16 f16;
typedef _Float16 f16x2 __attribute__((ext_vector_type(2)));
typedef _Float16 f16x4 __attribute__((ext_vector_type(4)));
typedef _Float16 f16x8 __attribute__((ext_vector_type(8)));
typedef float f32x16 __attribute__((ext_vector_type(16)));
typedef float v2f __attribute__((ext_vector_type(2)));

// ---------------- fused prep: fuse | fuse_bias+init | expand | wcvt | vt ----------------
__global__ __launch_bounds__(256) void k_prep(
    const float* __restrict__ Wq_w, const float* __restrict__ proj_w,
    const float* __restrict__ Wq_b, const float* __restrict__ proj_b,
    const float* __restrict__ Wo_w, const float* __restrict__ V,
    f16* __restrict__ Mf, f16* __restrict__ Mkf,
    float* __restrict__ cbias, float* __restrict__ pbias,
    f16* __restrict__ Wf, f16* __restrict__ Vt2, float* __restrict__ khm) {
  __shared__ f16 tile[64][72];
  const int bid = blockIdx.x;
  const int t = threadIdx.x;
  if (bid < 384) {
    int tid = bid * 256 + t;
    int hj = tid >> 10, d = tid & 1023;
    int h = hj / NJ, j = hj - h * NJ;
    const float* wq = Wq_w + (size_t)(h * DK_) * D_ + d;
    const float* pw = proj_w + j * DK_;
    float acc = 0.f;
#pragma unroll 8
    for (int k = 0; k < DK_; ++k) acc += wq[(size_t)k * D_] * pw[k];
    Mf[(size_t)hj * D_ + d] = (f16)acc;
  } else if (bid == 384) {
    if (t < NG) {
      int h = t / NJ, j = t - h * NJ;
      float acc = proj_b[j];
      for (int k = 0; k < DK_; ++k) acc += Wq_b[h * DK_ + k] * proj_w[j * DK_ + k];
      cbias[t] = acc;
      pbias[t] = proj_b[j];
    }
    if (t < 8) ((unsigned int*)khm)[t] = 0u;  // atomicMax identity (kn2 >= 0)
  } else if (bid < 769) {
    int tid = (bid - 385) * 256 + t;
    int hj = tid >> 10, d = tid & 1023;
    int h = hj / NJ, j = hj - h * NJ;
    float v = ((d >> 8) == h) ? proj_w[j * DK_ + (d & 255)] : 0.f;
    Mkf[tid] = (f16)v;
  } else if (bid < 1281) {
    int i = ((bid - 769) * 256 + t) * 8;
    float4 a = *(const float4*)(Wo_w + i);
    float4 b = *(const float4*)(Wo_w + i + 4);
    f16x8 o = {(f16)a.x, (f16)a.y, (f16)a.z, (f16)a.w,
               (f16)b.x, (f16)b.y, (f16)b.z, (f16)b.w};
    *(f16x8*)(Wf + i) = o;
  } else {
    int vbid = bid - 1281;
    int s0 = (vbid & 31) * 64, c0 = ((vbid >> 5) & 3) * 64;
    int bh = vbid >> 7;
    int b = bh >> 2, h = bh & 3;
    const float* src = V + (size_t)b * S_ * D_ + h * DK_ + c0;
#pragma unroll
    for (int u = 0; u < 4; ++u) {
      int row = (t >> 4) + 16 * u;
      int c4 = (t & 15) * 4;
      float4 v = *(const float4*)(src + (size_t)(s0 + row) * D_ + c4);
      tile[c4 + 0][row] = (f16)v.x;
      tile[c4 + 1][row] = (f16)v.y;
      tile[c4 + 2][row] = (f16)v.z;
      tile[c4 + 3][row] = (f16)v.w;
    }
    __syncthreads();
#pragma unroll
    for (int u = 0; u < 2; ++u) {
      int sid = t + 256 * u;
      int sgroup = sid & 7, dkl = sid >> 3;
      int dk = c0 + dkl, s = s0 + sgroup * 8;
      int wv = dk >> 5, qq = dk & 31;
      int kt = s >> 7, ks = (s >> 4) & 7, lhh = (s >> 3) & 1;
      size_t idx = ((((size_t)(bh * 8 + wv) * 16 + kt) * 8 + ks) * 2 + lhh) * 256 + qq * 8;
      *(f16x8*)(Vt2 + idx) = *(const f16x8*)&tile[dkl][sgroup * 8];
    }
  }
}

// ---------------- unified gen via f16 MFMA + psi (+ fused khmax atomics) ----------------
__global__ __launch_bounds__(256, 1) void k_gen(
    const float* __restrict__ Q, const float* __restrict__ Kin,
    const f16* __restrict__ Mf, const f16* __restrict__ Mkf,
    const float* __restrict__ cbias, const float* __restrict__ pbias,
    f16* __restrict__ pqF, float* __restrict__ qn2,
    f16* __restrict__ pkF, float* __restrict__ kn2,
    float* __restrict__ khm) {
  __shared__ __align__(16) f16 Xs[8192];
  __shared__ __align__(16) f16 Bs[24576];
  __shared__ __align__(16) float redP[4][32][96];
  __shared__ float genL[32][100];

  const int t = threadIdx.x;
  const int w = t >> 6, lane = t & 63;
  const int l31 = lane & 31, lh = lane >> 5;
  const bool isQ = blockIdx.x < 128;
  const int r0 = (isQ ? blockIdx.x : blockIdx.x - 128) * 32;
  const float* X = isQ ? Q : Kin;
  const f16* Bf = isQ ? Mf : Mkf;
  const float* bias = isQ ? cbias : pbias;

  int xrow[8], xk4[8];
#pragma unroll
  for (int u = 0; u < 8; ++u) {
    int idx = t + 256 * u;
    xrow[u] = idx >> 6;
    xk4[u] = idx & 63;
  }
  int bcol[12], bkg[12];
#pragma unroll
  for (int u = 0; u < 12; ++u) {
    int idx = t + 256 * u;
    bcol[u] = idx >> 5;
    bkg[u] = idx & 31;
  }

  float4 xr[8];
  f16x8 br[12];
#define XLOAD(K0)                                                              \
  {                                                                            \
    _Pragma("unroll") for (int u = 0; u < 8; ++u) xr[u] =                      \
        *(const float4*)(X + (size_t)(r0 + xrow[u]) * D_ + (K0) + xk4[u] * 4); \
  }
#define BLOAD(K0)                                                            \
  {                                                                          \
    _Pragma("unroll") for (int u = 0; u < 12; ++u) br[u] =                   \
        *(const f16x8*)(Bf + (size_t)bcol[u] * D_ + (K0) + bkg[u] * 8);      \
  }
#define XWRITE()                                                            \
  {                                                                         \
    _Pragma("unroll") for (int u = 0; u < 8; ++u) {                         \
      f16x4 v = {(f16)xr[u].x, (f16)xr[u].y, (f16)xr[u].z, (f16)xr[u].w};   \
      *(f16x4*)&Xs[((xk4[u] >> 1) * 32 + xrow[u]) * 8 + (xk4[u] & 1) * 4] = v; \
    }                                                                       \
  }
#define BWRITE()                                                            \
  {                                                                         \
    _Pragma("unroll") for (int u = 0; u < 12; ++u)                          \
        *(f16x8*)&Bs[(bcol[u] >> 5) * 8192 + bkg[u] * 256 +                 \
                     (bcol[u] & 31) * 8] = br[u];                           \
  }

  XLOAD(0);
  BLOAD(0);
  XWRITE();
  BWRITE();
  __syncthreads();

  f32x16 acc0{}, acc1{}, acc2{};
  for (int ch = 0; ch < 4; ++ch) {
    if (ch < 3) {
      XLOAD((ch + 1) * 256);
      BLOAD((ch + 1) * 256);
    }
#pragma unroll
    for (int i = 0; i < 4; ++i) {
      const int kk = w * 4 + i;
      const int off = (kk * 2 + lh) * 256 + l31 * 8;
      f16x8 af = *(const f16x8*)&Xs[off];
      f16x8 b0 = *(const f16x8*)&Bs[off];
      f16x8 b1 = *(const f16x8*)&Bs[8192 + off];
      f16x8 b2 = *(const f16x8*)&Bs[16384 + off];
      acc0 = __builtin_amdgcn_mfma_f32_32x32x16_f16(af, b0, acc0, 0, 0, 0);
      acc1 = __builtin_amdgcn_mfma_f32_32x32x16_f16(af, b1, acc1, 0, 0, 0);
      acc2 = __builtin_amdgcn_mfma_f32_32x32x16_f16(af, b2, acc2, 0, 0, 0);
    }
    __syncthreads();
    if (ch < 3) {
      XWRITE();
      BWRITE();
      __syncthreads();
    }
  }
#undef XLOAD
#undef BLOAD
#undef XWRITE
#undef BWRITE

#pragma unroll
  for (int r = 0; r < 16; ++r) {
    const int row = (r & 3) + 8 * (r >> 2) + 4 * lh;
    redP[w][row][l31] = acc0[r];
    redP[w][row][32 + l31] = acc1[r];
    redP[w][row][64 + l31] = acc2[r];
  }
  __syncthreads();

  {
    const int row = t >> 3, cg = t & 7;
#pragma unroll
    for (int c = 0; c < 12; ++c) {
      int col = cg * 12 + c;
      genL[row][col] = redP[0][row][col] + redP[1][row][col] +
                       redP[2][row][col] + redP[3][row][col] + bias[col];
    }
  }
  __syncthreads();

  {
    const int rg = t >> 6;
    const int hh = (t & 63) >> 4;
    const int ii = t & 15;
    const int j = ii & 7;
    f16* po = isQ ? pqF : pkF;
    float* n2o = isQ ? qn2 : kn2;
    float mx = 0.f;
#pragma unroll 2
    for (int r = 0; r < 8; ++r) {
      int row = rg * 8 + r;
      int g = r0 + row;
      int b = g >> 11, s = g & (S_ - 1);
      const float* gl = &genL[row][hh * NJ];
      float A = gl[j], Bg = gl[8 + j];
      float Th = fminf(fmaxf(gl[16 + j], -8.f), 8.f);
      float val = (ii < 8) ? (A * expf(Th) + Bg * cosf(Th)) : (Bg * sinf(Th));
      size_t base = (size_t)(b * H_ + hh) * S_ + s;
      po[base * 16 + ii] = (f16)val;
      float sq = val * val;
#pragma unroll
      for (int off = 1; off < 16; off <<= 1) sq += __shfl_xor(sq, off);
      if (ii == 0) {
        n2o[base] = sq;
        mx = fmaxf(mx, sq);
      }
    }
    // fused khmax: uint atomicMax valid for non-negative floats
    if (!isQ && ii == 0) {
      int g = r0;
      int b = g >> 11;
      atomicMax((unsigned int*)&khm[b * H_ + hh], __float_as_uint(mx));
    }
  }
}

// ---------------- MFMA flash geometric attention, full-S, static-max softmax ----------------
// 512 blocks (bh = bid&7, qt = bid>>3); each walks all 16 K-tiles; writes
// normalized f16 attnF directly (no split-K partials, no merge kernel).
__global__ __launch_bounds__(512, 4) void k_attn(
    const f16* __restrict__ pqF, const float* __restrict__ qn2,
    const f16* __restrict__ pkF, const float* __restrict__ kn2,
    const f16* __restrict__ Vt2, const float* __restrict__ geo_w,
    const float* __restrict__ temp, const float* __restrict__ khm,
    f16* __restrict__ attnF) {
  __shared__ __align__(16) float kn2s[2][KTA];
  __shared__ __align__(16) float khs[2][KTA];
  __shared__ float sPart[8][32];
  __shared__ float linvL[32];
  __shared__ __align__(16) f16 Plds[2][16][32][8];

  const int t = threadIdx.x;
  const int w = t >> 6;
  const int lane = t & 63;
  const int q_ = lane & 31;
  const int lh = lane >> 5;

  const int bid = blockIdx.x;
  const int bh = bid & 7, qt = bid >> 3;
  const int q0 = qt * 32;
  const int b = bh >> 2, h = bh & 3;

  const size_t bhS = (size_t)bh * S_;
  const f16* pkb = pkF + bhS * 16;
  const float* kn2b = kn2 + bhS;

  const float scale = 0.25f / temp[0] * 1.4426950408889634f;
  const float g0s = geo_w[0] * scale, g1s = geo_w[1] * scale, g2s = geo_w[2] * scale;
  const float g3s = geo_w[3] * scale;

  const f16x8 bq = *(const f16x8*)(pqF + (bhS + q0 + q_) * 16 + lh * 8);
  const float qn2q = qn2[bhS + q0 + q_];
  const float qh = sqrtf(qn2q + 1e-6f);
  const float qh3 = qh * g3s;
  const float sumg = fabsf(g0s) + fabsf(g1s) + fabsf(g2s) + fabsf(g3s);
  const float Mhat = sumg * qh * sqrtf(khm[bh] + 1e-6f) - 4.328085123f;

  const v2f qn2v = {qn2q, qn2q};
  const v2f g0v = {g0s, g0s}, g1v = {g1s, g1s}, g2v = {g2s, g2s};
  const v2f zero2 = {0.f, 0.f}, eps2 = {1e-6f, 1e-6f};
  const v2f mhv = {Mhat, Mhat};

  const f16* ap_base = pkb + (size_t)(w * 16 + (q_ & 15)) * 16 +
                       ((q_ < 16) ? lh * 8 : (1 - lh) * 8);
  const f16* vb_lane = Vt2 + (size_t)(bh * 8 + w) * 16 * 4096 + lh * 256 + q_ * 8;

  if (t < KTA) { float kv = kn2b[t]; kn2s[0][t] = kv; khs[0][t] = sqrtf(kv + 1e-6f); }
  float lreg = 0.f;
  f32x16 acc{};
  const f32x16 zacc{};

  f16x8 af = *(const f16x8*)ap_base;
  f16x8 bv[8];
#pragma unroll
  for (int ks = 0; ks < 8; ++ks) bv[ks] = *(const f16x8*)(vb_lane + ks * 512);
  __syncthreads();

  for (int ktl = 0; ktl < NT2; ++ktl) {
    const int k0l = ktl * KTA;
    const int cb = ktl & 1, nb = cb ^ 1;

    float knv = 0.f;
    if (t < KTA && ktl + 1 < NT2) knv = kn2b[k0l + KTA + t];

    f16x8 afx = af;
    if (q_ >= 16 && lh == 1) afx = -afx;
    __builtin_amdgcn_s_setprio(1);
    f32x16 sc = __builtin_amdgcn_mfma_f32_32x32x16_f16(afx, bq, zacc, 0, 0, 0);
    __builtin_amdgcn_s_setprio(0);
    if (ktl + 1 < NT2) af = *(const f16x8*)(ap_base + (size_t)(k0l + KTA) * 16);

    float pv[8];
    v2f psv = {0.f, 0.f};
#pragma unroll
    for (int rp = 0; rp < 4; ++rp) {
      const int r = 2 * rp;
      const int kb2 = w * 16 + 4 * lh + (rp & 1) * 2 + (rp >> 1) * 8;
      v2f tn = {sc[r], sc[r + 1]};
      v2f sp = {sc[r + 8], sc[r + 9]};
      v2f kn2p = *(const v2f*)&kn2s[cb][kb2];
      v2f khp = *(const v2f*)&khs[cb][kb2];
      v2f wr = qn2v * kn2p - tn * tn - sp * sp;
      wr = __builtin_elementwise_max(wr, zero2) + eps2;
      v2f wg = {sqrtf(wr.x), sqrtf(wr.y)};
      v2f sv2 = g0v * wg + g1v * tn + g2v * sp + qh3 * khp - mhv;
      v2f p2 = {exp2f(sv2.x), exp2f(sv2.y)};
      pv[r] = p2.x;
      pv[r + 1] = p2.y;
      psv += p2;
    }
    lreg += psv.x + psv.y;

    if (t < KTA && ktl + 1 < NT2) {
      kn2s[nb][t] = knv;
      khs[nb][t] = sqrtf(knv + 1e-6f);
    }
    {
      f16x2 p01 = {(f16)pv[0], (f16)pv[1]};
      f16x2 p23 = {(f16)pv[2], (f16)pv[3]};
      f16x2 p45 = {(f16)pv[4], (f16)pv[5]};
      f16x2 p67 = {(f16)pv[6], (f16)pv[7]};
      *(f16x2*)&Plds[cb][2 * w + 0][q_][4 * lh + 0] = p01;
      *(f16x2*)&Plds[cb][2 * w + 0][q_][4 * lh + 2] = p23;
      *(f16x2*)&Plds[cb][2 * w + 1][q_][4 * lh + 0] = p45;
      *(f16x2*)&Plds[cb][2 * w + 1][q_][4 * lh + 2] = p67;
    }
    __syncthreads();  // single barrier per tile

    __builtin_amdgcn_s_setprio(1);
#pragma unroll
    for (int ks = 0; ks < 8; ++ks) {
      f16x8 pa = *(const f16x8*)&Plds[cb][2 * ks + lh][q_][0];
      acc = __builtin_amdgcn_mfma_f32_32x32x16_f16(pa, bv[ks], acc, 0, 0, 0);
    }
    __builtin_amdgcn_s_setprio(0);
    if (ktl + 1 < NT2) {
      const f16* vbn = vb_lane + (size_t)(ktl + 1) * 4096;
#pragma unroll
      for (int ks = 0; ks < 8; ++ks) bv[ks] = *(const f16x8*)(vbn + ks * 512);
    }
  }

  // ---- l reduction -> per-q inverse, then direct normalized f16 output ----
  lreg += __shfl_xor(lreg, 32);
  if (lh == 0) sPart[w][q_] = lreg;
  __syncthreads();
  if (t < 32) {
    float s8 = 0.f;
#pragma unroll
    for (int i = 0; i < 8; ++i) s8 += sPart[i][t];
    linvL[t] = 1.f / s8;
  }
  __syncthreads();
  const size_t obase = ((size_t)b * S_ + q0) * D_ + h * DK_ + w * 32 + q_;
#pragma unroll
  for (int r = 0; r < 16; ++r) {
    const int row = (r & 3) + 8 * (r >> 2) + 4 * lh;
    attnF[obase + (size_t)row * D_] = (f16)(acc[r] * linvL[row]);
  }
}

// ---------------- output projection: LDS-staged f16 MFMA GEMM ----------------
__global__ __launch_bounds__(256, 1) void k_wo(const f16* __restrict__ A,
                                               const f16* __restrict__ Wt,
                                               const float* __restrict__ bias,
                                               float* __restrict__ C) {
  __shared__ __align__(16) f16 Abuf[2][128 * 64];
  __shared__ __align__(16) f16 Bbuf[2][128 * 64];
  const int t = threadIdx.x;
  const int w = t >> 6, lane = t & 63;
  const int wr = w >> 1, wc = w & 1;
  const int brow = blockIdx.y * 128, bcol = blockIdx.x * 128;

  int srow[4], skof[4];
#pragma unroll
  for (int u = 0; u < 4; ++u) {
    int c = t + 256 * u;
    int sub = c >> 6, l6 = c & 63;
    srow[u] = (sub >> 2) * 32 + (l6 & 31);
    skof[u] = (sub & 3) * 16 + (l6 >> 5) * 8;
  }

  uint4 ra0, ra1, ra2, ra3, rb0, rb1, rb2, rb3;
#define LOAD_TILE(K0)                                                        \
  {                                                                          \
    ra0 = *(const uint4*)(A + (size_t)(brow + srow[0]) * D_ + (K0) + skof[0]); \
    ra1 = *(const uint4*)(A + (size_t)(brow + srow[1]) * D_ + (K0) + skof[1]); \
    ra2 = *(const uint4*)(A + (size_t)(brow + srow[2]) * D_ + (K0) + skof[2]); \
    ra3 = *(const uint4*)(A + (size_t)(brow + srow[3]) * D_ + (K0) + skof[3]); \
    rb0 = *(const uint4*)(Wt + (size_t)(bcol + srow[0]) * D_ + (K0) + skof[0]); \
    rb1 = *(const uint4*)(Wt + (size_t)(bcol + srow[1]) * D_ + (K0) + skof[1]); \
    rb2 = *(const uint4*)(Wt + (size_t)(bcol + srow[2]) * D_ + (K0) + skof[2]); \
    rb3 = *(const uint4*)(Wt + (size_t)(bcol + srow[3]) * D_ + (K0) + skof[3]); \
  }
#define WRITE_TILE(BUF)                                       \
  {                                                           \
    *(uint4*)&Abuf[BUF][(t + 0) * 8] = ra0;                   \
    *(uint4*)&Abuf[BUF][(t + 256) * 8] = ra1;                 \
    *(uint4*)&Abuf[BUF][(t + 512) * 8] = ra2;                 \
    *(uint4*)&Abuf[BUF][(t + 768) * 8] = ra3;                 \
    *(uint4*)&Bbuf[BUF][(t + 0) * 8] = rb0;                   \
    *(uint4*)&Bbuf[BUF][(t + 256) * 8] = rb1;                 \
    *(uint4*)&Bbuf[BUF][(t + 512) * 8] = rb2;                 \
    *(uint4*)&Bbuf[BUF][(t + 768) * 8] = rb3;                 \
  }

  f32x16 acc00{}, acc01{}, acc10{}, acc11{};

  LOAD_TILE(0);
  WRITE_TILE(0);
  LOAD_TILE(64);
  __syncthreads();

  int cur = 0;
  for (int kt = 0; kt < 16; ++kt) {
    const int am0 = (wr * 2 + 0) * 4, am1 = (wr * 2 + 1) * 4;
    const int bn0 = (wc * 2 + 0) * 4, bn1 = (wc * 2 + 1) * 4;
#pragma unroll
    for (int kk = 0; kk < 4; ++kk) {
      f16x8 a0 = *(const f16x8*)&Abuf[cur][(am0 + kk) * 512 + lane * 8];
      f16x8 a1 = *(const f16x8*)&Abuf[cur][(am1 + kk) * 512 + lane * 8];
      f16x8 b0 = *(const f16x8*)&Bbuf[cur][(bn0 + kk) * 512 + lane * 8];
      f16x8 b1 = *(const f16x8*)&Bbuf[cur][(bn1 + kk) * 512 + lane * 8];
      acc00 = __builtin_amdgcn_mfma_f32_32x32x16_f16(a0, b0, acc00, 0, 0, 0);
      acc01 = __builtin_amdgcn_mfma_f32_32x32x16_f16(a0, b1, acc01, 0, 0, 0);
      acc10 = __builtin_amdgcn_mfma_f32_32x32x16_f16(a1, b0, acc10, 0, 0, 0);
      acc11 = __builtin_amdgcn_mfma_f32_32x32x16_f16(a1, b1, acc11, 0, 0, 0);
    }
    if (kt + 1 < 16) {
      WRITE_TILE(cur ^ 1);
      if (kt + 2 < 16) LOAD_TILE((kt + 2) * 64);
    }
    __syncthreads();
    cur ^= 1;
  }

  const int l31 = lane & 31, lh = lane >> 5;
  const float bv0 = bias[bcol + (wc * 2 + 0) * 32 + l31];
  const float bv1 = bias[bcol + (wc * 2 + 1) * 32 + l31];
#pragma unroll
  for (int r = 0; r < 16; ++r) {
    const int row = (r & 3) + 8 * (r >> 2) + 4 * lh;
    const size_t m0r = (size_t)(brow + (wr * 2 + 0) * 32 + row) * D_;
    const size_t m1r = (size_t)(brow + (wr * 2 + 1) * 32 + row) * D_;
    C[m0r + bcol + (wc * 2 + 0) * 32 + l31] = acc00[r] + bv0;
    C[m0r + bcol + (wc * 2 + 1) * 32 + l31] = acc01[r] + bv1;
    C[m1r + bcol + (wc * 2 + 0) * 32 + l31] = acc10[r] + bv0;
    C[m1r + bcol + (wc * 2 + 1) * 32 + l31] = acc11[r] + bv1;
  }
#undef LOAD_TILE
#undef WRITE_TILE
}

extern "C" void kernel_launch(void* const* d_in, const int* in_sizes, int n_in,
                              void* d_out, int out_size, void* d_ws, size_t ws_size,
                              hipStream_t stream) {
  const float* Q_input = (const float*)d_in[0];
  const float* K = (const float*)d_in[1];
  const float* V = (const float*)d_in[2];
  const float* Wq_w = (const float*)d_in[4];
  const float* Wq_b = (const float*)d_in[5];
  const float* Wo_w = (const float*)d_in[6];
  const float* Wo_b = (const float*)d_in[7];
  const float* proj_w = (const float*)d_in[8];
  const float* proj_b = (const float*)d_in[9];
  const float* geo_w = (const float*)d_in[10];
  const float* temp = (const float*)d_in[11];

  float* ws = (float*)d_ws;
  float* cbias = ws;                       // 128 f32
  float* pbias = cbias + 128;              // 128
  float* khm = pbias + 128;                // 128 (8 used; stores max kn2)
  f16* Mf = (f16*)(khm + 128);             // 98304 f16
  f16* Mkf = Mf + 98304;                   // 98304 f16
  float* qn2 = (float*)(Mkf + 98304);      // 16384 f32
  float* kn2 = qn2 + 16384;                // 16384 f32
  f16* pqF = (f16*)(kn2 + 16384);          // 262144 f16
  f16* pkF = pqF + 262144;                 // 262144 f16
  f16* Vt2 = pkF + 262144;                 // 4194304 f16 (full B*S*D)
  f16* attnF = Vt2 + 4194304;              // 4194304 f16
  f16* Wf = attnF + 4194304;               // 1048576 f16
  float* out = (float*)d_out;

  k_prep<<<dim3(2305), dim3(256), 0, stream>>>(Wq_w, proj_w, Wq_b, proj_b, Wo_w,
                                               V, Mf, Mkf, cbias, pbias, Wf, Vt2,
                                               khm);
  k_gen<<<dim3(256), dim3(256), 0, stream>>>(Q_input, K, Mf, Mkf, cbias, pbias,
                                             pqF, qn2, pkF, kn2, khm);
  k_attn<<<dim3(512), dim3(512), 0, stream>>>(pqF, qn2, pkF, kn2, Vt2, geo_w,
                                              temp, khm, attnF);
  k_wo<<<dim3(8, 32), dim3(256), 0, stream>>>(attnF, Wf, Wo_b, out);
}

// Round 22
// 102.663 us; speedup vs baseline: 1.5394x; 1.1289x over previous
//
#include <hip/hip_runtime.h>
#include <hip/hip_bf16.h>
#include <math.h>

#define B_ 2
#define S_ 2048
#define D_ 1024
#define H_ 4
#define DK_ 256
#define NJ 24
#define NG 96
#define KTA 128
#define NT2 (S_ / KTA)

typedef _Float16 f16;
typedef _Float16 f16x2 __attribute__((ext_vector_type(2)));
typedef _Float16 f16x4 __attribute__((ext_vector_type(4)));
typedef _Float16 f16x8 __attribute__((ext_vector_type(8)));
typedef float f32x16 __attribute__((ext_vector_type(16)));
typedef float v2f __attribute__((ext_vector_type(2)));

// ---------------- fused prep: fuse | fuse_bias+init | expand | wcvt | vt ----------------
__global__ __launch_bounds__(256) void k_prep(
    const float* __restrict__ Wq_w, const float* __restrict__ proj_w,
    const float* __restrict__ Wq_b, const float* __restrict__ proj_b,
    const float* __restrict__ Wo_w, const float* __restrict__ V,
    f16* __restrict__ Mf, f16* __restrict__ Mkf,
    float* __restrict__ cbias, float* __restrict__ pbias,
    f16* __restrict__ Wf, f16* __restrict__ Vt2, float* __restrict__ khm) {
  __shared__ f16 tile[64][72];
  const int bid = blockIdx.x;
  const int t = threadIdx.x;
  if (bid < 384) {
    int tid = bid * 256 + t;
    int hj = tid >> 10, d = tid & 1023;
    int h = hj / NJ, j = hj - h * NJ;
    const float* wq = Wq_w + (size_t)(h * DK_) * D_ + d;
    const float* pw = proj_w + j * DK_;
    float acc = 0.f;
#pragma unroll 8
    for (int k = 0; k < DK_; ++k) acc += wq[(size_t)k * D_] * pw[k];
    Mf[(size_t)hj * D_ + d] = (f16)acc;
  } else if (bid == 384) {
    if (t < NG) {
      int h = t / NJ, j = t - h * NJ;
      float acc = proj_b[j];
      for (int k = 0; k < DK_; ++k) acc += Wq_b[h * DK_ + k] * proj_w[j * DK_ + k];
      cbias[t] = acc;
      pbias[t] = proj_b[j];
    }
    if (t < 8) ((unsigned int*)khm)[t] = 0u;  // atomicMax identity (kn2 >= 0)
  } else if (bid < 769) {
    int tid = (bid - 385) * 256 + t;
    int hj = tid >> 10, d = tid & 1023;
    int h = hj / NJ, j = hj - h * NJ;
    float v = ((d >> 8) == h) ? proj_w[j * DK_ + (d & 255)] : 0.f;
    Mkf[tid] = (f16)v;
  } else if (bid < 1281) {
    int i = ((bid - 769) * 256 + t) * 8;
    float4 a = *(const float4*)(Wo_w + i);
    float4 b = *(const float4*)(Wo_w + i + 4);
    f16x8 o = {(f16)a.x, (f16)a.y, (f16)a.z, (f16)a.w,
               (f16)b.x, (f16)b.y, (f16)b.z, (f16)b.w};
    *(f16x8*)(Wf + i) = o;
  } else {
    int vbid = bid - 1281;
    int s0 = (vbid & 31) * 64, c0 = ((vbid >> 5) & 3) * 64;
    int bh = vbid >> 7;
    int b = bh >> 2, h = bh & 3;
    const float* src = V + (size_t)b * S_ * D_ + h * DK_ + c0;
#pragma unroll
    for (int u = 0; u < 4; ++u) {
      int row = (t >> 4) + 16 * u;
      int c4 = (t & 15) * 4;
      float4 v = *(const float4*)(src + (size_t)(s0 + row) * D_ + c4);
      tile[c4 + 0][row] = (f16)v.x;
      tile[c4 + 1][row] = (f16)v.y;
      tile[c4 + 2][row] = (f16)v.z;
      tile[c4 + 3][row] = (f16)v.w;
    }
    __syncthreads();
#pragma unroll
    for (int u = 0; u < 2; ++u) {
      int sid = t + 256 * u;
      int sgroup = sid & 7, dkl = sid >> 3;
      int dk = c0 + dkl, s = s0 + sgroup * 8;
      int wv = dk >> 5, qq = dk & 31;
      int kt = s >> 7, ks = (s >> 4) & 7, lhh = (s >> 3) & 1;
      size_t idx = ((((size_t)(bh * 8 + wv) * 16 + kt) * 8 + ks) * 2 + lhh) * 256 + qq * 8;
      *(f16x8*)(Vt2 + idx) = *(const f16x8*)&tile[dkl][sgroup * 8];
    }
  }
}

// ---------------- unified gen via f16 MFMA + psi (+ fused khmax atomics) ----------------
__global__ __launch_bounds__(256, 1) void k_gen(
    const float* __restrict__ Q, const float* __restrict__ Kin,
    const f16* __restrict__ Mf, const f16* __restrict__ Mkf,
    const float* __restrict__ cbias, const float* __restrict__ pbias,
    f16* __restrict__ pqF, float* __restrict__ qn2,
    f16* __restrict__ pkF, float* __restrict__ kn2,
    float* __restrict__ khm) {
  __shared__ __align__(16) f16 Xs[8192];
  __shared__ __align__(16) f16 Bs[24576];
  __shared__ __align__(16) float redP[4][32][96];
  __shared__ float genL[32][100];

  const int t = threadIdx.x;
  const int w = t >> 6, lane = t & 63;
  const int l31 = lane & 31, lh = lane >> 5;
  const bool isQ = blockIdx.x < 128;
  const int r0 = (isQ ? blockIdx.x : blockIdx.x - 128) * 32;
  const float* X = isQ ? Q : Kin;
  const f16* Bf = isQ ? Mf : Mkf;
  const float* bias = isQ ? cbias : pbias;

  int xrow[8], xk4[8];
#pragma unroll
  for (int u = 0; u < 8; ++u) {
    int idx = t + 256 * u;
    xrow[u] = idx >> 6;
    xk4[u] = idx & 63;
  }
  int bcol[12], bkg[12];
#pragma unroll
  for (int u = 0; u < 12; ++u) {
    int idx = t + 256 * u;
    bcol[u] = idx >> 5;
    bkg[u] = idx & 31;
  }

  float4 xr[8];
  f16x8 br[12];
#define XLOAD(K0)                                                              \
  {                                                                            \
    _Pragma("unroll") for (int u = 0; u < 8; ++u) xr[u] =                      \
        *(const float4*)(X + (size_t)(r0 + xrow[u]) * D_ + (K0) + xk4[u] * 4); \
  }
#define BLOAD(K0)                                                            \
  {                                                                          \
    _Pragma("unroll") for (int u = 0; u < 12; ++u) br[u] =                   \
        *(const f16x8*)(Bf + (size_t)bcol[u] * D_ + (K0) + bkg[u] * 8);      \
  }
#define XWRITE()                                                            \
  {                                                                         \
    _Pragma("unroll") for (int u = 0; u < 8; ++u) {                         \
      f16x4 v = {(f16)xr[u].x, (f16)xr[u].y, (f16)xr[u].z, (f16)xr[u].w};   \
      *(f16x4*)&Xs[((xk4[u] >> 1) * 32 + xrow[u]) * 8 + (xk4[u] & 1) * 4] = v; \
    }                                                                       \
  }
#define BWRITE()                                                            \
  {                                                                         \
    _Pragma("unroll") for (int u = 0; u < 12; ++u)                          \
        *(f16x8*)&Bs[(bcol[u] >> 5) * 8192 + bkg[u] * 256 +                 \
                     (bcol[u] & 31) * 8] = br[u];                           \
  }

  XLOAD(0);
  BLOAD(0);
  XWRITE();
  BWRITE();
  __syncthreads();

  f32x16 acc0{}, acc1{}, acc2{};
  for (int ch = 0; ch < 4; ++ch) {
    if (ch < 3) {
      XLOAD((ch + 1) * 256);
      BLOAD((ch + 1) * 256);
    }
#pragma unroll
    for (int i = 0; i < 4; ++i) {
      const int kk = w * 4 + i;
      const int off = (kk * 2 + lh) * 256 + l31 * 8;
      f16x8 af = *(const f16x8*)&Xs[off];
      f16x8 b0 = *(const f16x8*)&Bs[off];
      f16x8 b1 = *(const f16x8*)&Bs[8192 + off];
      f16x8 b2 = *(const f16x8*)&Bs[16384 + off];
      acc0 = __builtin_amdgcn_mfma_f32_32x32x16_f16(af, b0, acc0, 0, 0, 0);
      acc1 = __builtin_amdgcn_mfma_f32_32x32x16_f16(af, b1, acc1, 0, 0, 0);
      acc2 = __builtin_amdgcn_mfma_f32_32x32x16_f16(af, b2, acc2, 0, 0, 0);
    }
    __syncthreads();
    if (ch < 3) {
      XWRITE();
      BWRITE();
      __syncthreads();
    }
  }
#undef XLOAD
#undef BLOAD
#undef XWRITE
#undef BWRITE

#pragma unroll
  for (int r = 0; r < 16; ++r) {
    const int row = (r & 3) + 8 * (r >> 2) + 4 * lh;
    redP[w][row][l31] = acc0[r];
    redP[w][row][32 + l31] = acc1[r];
    redP[w][row][64 + l31] = acc2[r];
  }
  __syncthreads();

  {
    const int row = t >> 3, cg = t & 7;
#pragma unroll
    for (int c = 0; c < 12; ++c) {
      int col = cg * 12 + c;
      genL[row][col] = redP[0][row][col] + redP[1][row][col] +
                       redP[2][row][col] + redP[3][row][col] + bias[col];
    }
  }
  __syncthreads();

  {
    const int rg = t >> 6;
    const int hh = (t & 63) >> 4;
    const int ii = t & 15;
    const int j = ii & 7;
    f16* po = isQ ? pqF : pkF;
    float* n2o = isQ ? qn2 : kn2;
    float mx = 0.f;
#pragma unroll 2
    for (int r = 0; r < 8; ++r) {
      int row = rg * 8 + r;
      int g = r0 + row;
      int b = g >> 11, s = g & (S_ - 1);
      const float* gl = &genL[row][hh * NJ];
      float A = gl[j], Bg = gl[8 + j];
      float Th = fminf(fmaxf(gl[16 + j], -8.f), 8.f);
      float val = (ii < 8) ? (A * __expf(Th) + Bg * __cosf(Th)) : (Bg * __sinf(Th));
      size_t base = (size_t)(b * H_ + hh) * S_ + s;
      po[base * 16 + ii] = (f16)val;
      float sq = val * val;
#pragma unroll
      for (int off = 1; off < 16; off <<= 1) sq += __shfl_xor(sq, off);
      if (ii == 0) {
        n2o[base] = sq;
        mx = fmaxf(mx, sq);
      }
    }
    // fused khmax: uint atomicMax valid for non-negative floats
    if (!isQ && ii == 0) {
      int g = r0;
      int b = g >> 11;
      atomicMax((unsigned int*)&khm[b * H_ + hh], __float_as_uint(mx));
    }
  }
}

// ---------------- MFMA flash geometric attention, full-S, static-max softmax ----------------
// 512 blocks (bh = bid&7, qt = bid>>3); fast HW sqrt/exp2 (args in safe ranges:
// wr >= 1e-6; exp2 arg <= 0, denormal flush below -126 is desired underflow).
__global__ __launch_bounds__(512, 4) void k_attn(
    const f16* __restrict__ pqF, const float* __restrict__ qn2,
    const f16* __restrict__ pkF, const float* __restrict__ kn2,
    const f16* __restrict__ Vt2, const float* __restrict__ geo_w,
    const float* __restrict__ temp, const float* __restrict__ khm,
    f16* __restrict__ attnF) {
  __shared__ __align__(16) float kn2s[2][KTA];
  __shared__ __align__(16) float khs[2][KTA];
  __shared__ float sPart[8][32];
  __shared__ float linvL[32];
  __shared__ __align__(16) f16 Plds[2][16][32][8];

  const int t = threadIdx.x;
  const int w = t >> 6;
  const int lane = t & 63;
  const int q_ = lane & 31;
  const int lh = lane >> 5;

  const int bid = blockIdx.x;
  const int bh = bid & 7, qt = bid >> 3;
  const int q0 = qt * 32;
  const int b = bh >> 2, h = bh & 3;

  const size_t bhS = (size_t)bh * S_;
  const f16* pkb = pkF + bhS * 16;
  const float* kn2b = kn2 + bhS;

  const float scale = 0.25f / temp[0] * 1.4426950408889634f;
  const float g0s = geo_w[0] * scale, g1s = geo_w[1] * scale, g2s = geo_w[2] * scale;
  const float g3s = geo_w[3] * scale;

  const f16x8 bq = *(const f16x8*)(pqF + (bhS + q0 + q_) * 16 + lh * 8);
  const float qn2q = qn2[bhS + q0 + q_];
  const float qh = sqrtf(qn2q + 1e-6f);
  const float qh3 = qh * g3s;
  const float sumg = fabsf(g0s) + fabsf(g1s) + fabsf(g2s) + fabsf(g3s);
  const float Mhat = sumg * qh * sqrtf(khm[bh] + 1e-6f) - 4.328085123f;

  const v2f qn2v = {qn2q, qn2q};
  const v2f g0v = {g0s, g0s}, g1v = {g1s, g1s}, g2v = {g2s, g2s};
  const v2f zero2 = {0.f, 0.f}, eps2 = {1e-6f, 1e-6f};
  const v2f mhv = {Mhat, Mhat};

  const f16* ap_base = pkb + (size_t)(w * 16 + (q_ & 15)) * 16 +
                       ((q_ < 16) ? lh * 8 : (1 - lh) * 8);
  const f16* vb_lane = Vt2 + (size_t)(bh * 8 + w) * 16 * 4096 + lh * 256 + q_ * 8;

  if (t < KTA) {
    float kv = kn2b[t];
    kn2s[0][t] = kv;
    khs[0][t] = __builtin_amdgcn_sqrtf(kv + 1e-6f);
  }
  float lreg = 0.f;
  f32x16 acc{};
  const f32x16 zacc{};

  f16x8 af = *(const f16x8*)ap_base;
  f16x8 bv[8];
#pragma unroll
  for (int ks = 0; ks < 8; ++ks) bv[ks] = *(const f16x8*)(vb_lane + ks * 512);
  __syncthreads();

  for (int ktl = 0; ktl < NT2; ++ktl) {
    const int k0l = ktl * KTA;
    const int cb = ktl & 1, nb = cb ^ 1;

    float knv = 0.f;
    if (t < KTA && ktl + 1 < NT2) knv = kn2b[k0l + KTA + t];

    f16x8 afx = af;
    if (q_ >= 16 && lh == 1) afx = -afx;
    __builtin_amdgcn_s_setprio(1);
    f32x16 sc = __builtin_amdgcn_mfma_f32_32x32x16_f16(afx, bq, zacc, 0, 0, 0);
    __builtin_amdgcn_s_setprio(0);
    if (ktl + 1 < NT2) af = *(const f16x8*)(ap_base + (size_t)(k0l + KTA) * 16);

    float pv[8];
    v2f psv = {0.f, 0.f};
#pragma unroll
    for (int rp = 0; rp < 4; ++rp) {
      const int r = 2 * rp;
      const int kb2 = w * 16 + 4 * lh + (rp & 1) * 2 + (rp >> 1) * 8;
      v2f tn = {sc[r], sc[r + 1]};
      v2f sp = {sc[r + 8], sc[r + 9]};
      v2f kn2p = *(const v2f*)&kn2s[cb][kb2];
      v2f khp = *(const v2f*)&khs[cb][kb2];
      v2f wr = qn2v * kn2p - tn * tn - sp * sp;
      wr = __builtin_elementwise_max(wr, zero2) + eps2;
      v2f wg = {__builtin_amdgcn_sqrtf(wr.x), __builtin_amdgcn_sqrtf(wr.y)};
      v2f sv2 = g0v * wg + g1v * tn + g2v * sp + qh3 * khp - mhv;
      v2f p2 = {__builtin_amdgcn_exp2f(sv2.x), __builtin_amdgcn_exp2f(sv2.y)};
      pv[r] = p2.x;
      pv[r + 1] = p2.y;
      psv += p2;
    }
    lreg += psv.x + psv.y;

    if (t < KTA && ktl + 1 < NT2) {
      kn2s[nb][t] = knv;
      khs[nb][t] = __builtin_amdgcn_sqrtf(knv + 1e-6f);
    }
    {
      f16x2 p01 = {(f16)pv[0], (f16)pv[1]};
      f16x2 p23 = {(f16)pv[2], (f16)pv[3]};
      f16x2 p45 = {(f16)pv[4], (f16)pv[5]};
      f16x2 p67 = {(f16)pv[6], (f16)pv[7]};
      *(f16x2*)&Plds[cb][2 * w + 0][q_][4 * lh + 0] = p01;
      *(f16x2*)&Plds[cb][2 * w + 0][q_][4 * lh + 2] = p23;
      *(f16x2*)&Plds[cb][2 * w + 1][q_][4 * lh + 0] = p45;
      *(f16x2*)&Plds[cb][2 * w + 1][q_][4 * lh + 2] = p67;
    }
    __syncthreads();  // single barrier per tile

    __builtin_amdgcn_s_setprio(1);
#pragma unroll
    for (int ks = 0; ks < 8; ++ks) {
      f16x8 pa = *(const f16x8*)&Plds[cb][2 * ks + lh][q_][0];
      acc = __builtin_amdgcn_mfma_f32_32x32x16_f16(pa, bv[ks], acc, 0, 0, 0);
    }
    __builtin_amdgcn_s_setprio(0);
    if (ktl + 1 < NT2) {
      const f16* vbn = vb_lane + (size_t)(ktl + 1) * 4096;
#pragma unroll
      for (int ks = 0; ks < 8; ++ks) bv[ks] = *(const f16x8*)(vbn + ks * 512);
    }
  }

  // ---- l reduction -> per-q inverse, then direct normalized f16 output ----
  lreg += __shfl_xor(lreg, 32);
  if (lh == 0) sPart[w][q_] = lreg;
  __syncthreads();
  if (t < 32) {
    float s8 = 0.f;
#pragma unroll
    for (int i = 0; i < 8; ++i) s8 += sPart[i][t];
    linvL[t] = 1.f / s8;
  }
  __syncthreads();
  const size_t obase = ((size_t)b * S_ + q0) * D_ + h * DK_ + w * 32 + q_;
#pragma unroll
  for (int r = 0; r < 16; ++r) {
    const int row = (r & 3) + 8 * (r >> 2) + 4 * lh;
    attnF[obase + (size_t)row * D_] = (f16)(acc[r] * linvL[row]);
  }
}

// ---------------- output projection: LDS-staged f16 MFMA GEMM ----------------
__global__ __launch_bounds__(256, 1) void k_wo(const f16* __restrict__ A,
                                               const f16* __restrict__ Wt,
                                               const float* __restrict__ bias,
                                               float* __restrict__ C) {
  __shared__ __align__(16) f16 Abuf[2][128 * 64];
  __shared__ __align__(16) f16 Bbuf[2][128 * 64];
  const int t = threadIdx.x;
  const int w = t >> 6, lane = t & 63;
  const int wr = w >> 1, wc = w & 1;
  const int brow = blockIdx.y * 128, bcol = blockIdx.x * 128;

  int srow[4], skof[4];
#pragma unroll
  for (int u = 0; u < 4; ++u) {
    int c = t + 256 * u;
    int sub = c >> 6, l6 = c & 63;
    srow[u] = (sub >> 2) * 32 + (l6 & 31);
    skof[u] = (sub & 3) * 16 + (l6 >> 5) * 8;
  }

  uint4 ra0, ra1, ra2, ra3, rb0, rb1, rb2, rb3;
#define LOAD_TILE(K0)                                                        \
  {                                                                          \
    ra0 = *(const uint4*)(A + (size_t)(brow + srow[0]) * D_ + (K0) + skof[0]); \
    ra1 = *(const uint4*)(A + (size_t)(brow + srow[1]) * D_ + (K0) + skof[1]); \
    ra2 = *(const uint4*)(A + (size_t)(brow + srow[2]) * D_ + (K0) + skof[2]); \
    ra3 = *(const uint4*)(A + (size_t)(brow + srow[3]) * D_ + (K0) + skof[3]); \
    rb0 = *(const uint4*)(Wt + (size_t)(bcol + srow[0]) * D_ + (K0) + skof[0]); \
    rb1 = *(const uint4*)(Wt + (size_t)(bcol + srow[1]) * D_ + (K0) + skof[1]); \
    rb2 = *(const uint4*)(Wt + (size_t)(bcol + srow[2]) * D_ + (K0) + skof[2]); \
    rb3 = *(const uint4*)(Wt + (size_t)(bcol + srow[3]) * D_ + (K0) + skof[3]); \
  }
#define WRITE_TILE(BUF)                                       \
  {                                                           \
    *(uint4*)&Abuf[BUF][(t + 0) * 8] = ra0;                   \
    *(uint4*)&Abuf[BUF][(t + 256) * 8] = ra1;                 \
    *(uint4*)&Abuf[BUF][(t + 512) * 8] = ra2;                 \
    *(uint4*)&Abuf[BUF][(t + 768) * 8] = ra3;                 \
    *(uint4*)&Bbuf[BUF][(t + 0) * 8] = rb0;                   \
    *(uint4*)&Bbuf[BUF][(t + 256) * 8] = rb1;                 \
    *(uint4*)&Bbuf[BUF][(t + 512) * 8] = rb2;                 \
    *(uint4*)&Bbuf[BUF][(t + 768) * 8] = rb3;                 \
  }

  f32x16 acc00{}, acc01{}, acc10{}, acc11{};

  LOAD_TILE(0);
  WRITE_TILE(0);
  LOAD_TILE(64);
  __syncthreads();

  int cur = 0;
  for (int kt = 0; kt < 16; ++kt) {
    const int am0 = (wr * 2 + 0) * 4, am1 = (wr * 2 + 1) * 4;
    const int bn0 = (wc * 2 + 0) * 4, bn1 = (wc * 2 + 1) * 4;
#pragma unroll
    for (int kk = 0; kk < 4; ++kk) {
      f16x8 a0 = *(const f16x8*)&Abuf[cur][(am0 + kk) * 512 + lane * 8];
      f16x8 a1 = *(const f16x8*)&Abuf[cur][(am1 + kk) * 512 + lane * 8];
      f16x8 b0 = *(const f16x8*)&Bbuf[cur][(bn0 + kk) * 512 + lane * 8];
      f16x8 b1 = *(const f16x8*)&Bbuf[cur][(bn1 + kk) * 512 + lane * 8];
      acc00 = __builtin_amdgcn_mfma_f32_32x32x16_f16(a0, b0, acc00, 0, 0, 0);
      acc01 = __builtin_amdgcn_mfma_f32_32x32x16_f16(a0, b1, acc01, 0, 0, 0);
      acc10 = __builtin_amdgcn_mfma_f32_32x32x16_f16(a1, b0, acc10, 0, 0, 0);
      acc11 = __builtin_amdgcn_mfma_f32_32x32x16_f16(a1, b1, acc11, 0, 0, 0);
    }
    if (kt + 1 < 16) {
      WRITE_TILE(cur ^ 1);
      if (kt + 2 < 16) LOAD_TILE((kt + 2) * 64);
    }
    __syncthreads();
    cur ^= 1;
  }

  const int l31 = lane & 31, lh = lane >> 5;
  const float bv0 = bias[bcol + (wc * 2 + 0) * 32 + l31];
  const float bv1 = bias[bcol + (wc * 2 + 1) * 32 + l31];
#pragma unroll
  for (int r = 0; r < 16; ++r) {
    const int row = (r & 3) + 8 * (r >> 2) + 4 * lh;
    const size_t m0r = (size_t)(brow + (wr * 2 + 0) * 32 + row) * D_;
    const size_t m1r = (size_t)(brow + (wr * 2 + 1) * 32 + row) * D_;
    C[m0r + bcol + (wc * 2 + 0) * 32 + l31] = acc00[r] + bv0;
    C[m0r + bcol + (wc * 2 + 1) * 32 + l31] = acc01[r] + bv1;
    C[m1r + bcol + (wc * 2 + 0) * 32 + l31] = acc10[r] + bv0;
    C[m1r + bcol + (wc * 2 + 1) * 32 + l31] = acc11[r] + bv1;
  }
#undef LOAD_TILE
#undef WRITE_TILE
}

extern "C" void kernel_launch(void* const* d_in, const int* in_sizes, int n_in,
                              void* d_out, int out_size, void* d_ws, size_t ws_size,
                              hipStream_t stream) {
  const float* Q_input = (const float*)d_in[0];
  const float* K = (const float*)d_in[1];
  const float* V = (const float*)d_in[2];
  const float* Wq_w = (const float*)d_in[4];
  const float* Wq_b = (const float*)d_in[5];
  const float* Wo_w = (const float*)d_in[6];
  const float* Wo_b = (const float*)d_in[7];
  const float* proj_w = (const float*)d_in[8];
  const float* proj_b = (const float*)d_in[9];
  const float* geo_w = (const float*)d_in[10];
  const float* temp = (const float*)d_in[11];

  float* ws = (float*)d_ws;
  float* cbias = ws;                       // 128 f32
  float* pbias = cbias + 128;              // 128
  float* khm = pbias + 128;                // 128 (8 used; stores max kn2)
  f16* Mf = (f16*)(khm + 128);             // 98304 f16
  f16* Mkf = Mf + 98304;                   // 98304 f16
  float* qn2 = (float*)(Mkf + 98304);      // 16384 f32
  float* kn2 = qn2 + 16384;                // 16384 f32
  f16* pqF = (f16*)(kn2 + 16384);          // 262144 f16
  f16* pkF = pqF + 262144;                 // 262144 f16
  f16* Vt2 = pkF + 262144;                 // 4194304 f16 (full B*S*D)
  f16* attnF = Vt2 + 4194304;              // 4194304 f16
  f16* Wf = attnF + 4194304;               // 1048576 f16
  float* out = (float*)d_out;

  k_prep<<<dim3(2305), dim3(256), 0, stream>>>(Wq_w, proj_w, Wq_b, proj_b, Wo_w,
                                               V, Mf, Mkf, cbias, pbias, Wf, Vt2,
                                               khm);
  k_gen<<<dim3(256), dim3(256), 0, stream>>>(Q_input, K, Mf, Mkf, cbias, pbias,
                                             pqF, qn2, pkF, kn2, khm);
  k_attn<<<dim3(512), dim3(512), 0, stream>>>(pqF, qn2, pkF, kn2, Vt2, geo_w,
                                              temp, khm, attnF);
  k_wo<<<dim3(8, 32), dim3(256), 0, stream>>>(attnF, Wf, Wo_b, out);
}